// Round 1
// baseline (1430.971 us; speedup 1.0000x reference)
//
#include <hip/hip_runtime.h>

static constexpr int NN = 50000;   // nodes
static constexpr int NE = 800000;  // edges
static constexpr int NG = 512;     // graphs
// HID = 128, 3 blocks x 2 inner convs

// ---------------------------------------------------------------- histogram
__global__ void hist_kernel(const int* __restrict__ dst, const float* __restrict__ ew,
                            float* __restrict__ deg, int* __restrict__ cnt, int nE)
{
    int i = blockIdx.x * blockDim.x + threadIdx.x;
    if (i < nE) {
        int d = dst[i];
        atomicAdd(&deg[d], ew[i]);
        atomicAdd(&cnt[d], 1);
    }
}

__global__ void dinv_kernel(const float* __restrict__ deg, float* __restrict__ dinv, int n)
{
    int i = blockIdx.x * blockDim.x + threadIdx.x;
    if (i < n) dinv[i] = rsqrtf(deg[i] + 1.0f);
}

// single-block exclusive scan over cnt -> rowptr (n = 50000, tiny)
__global__ __launch_bounds__(1024) void scan_kernel(const int* __restrict__ cnt,
                                                    int* __restrict__ rowptr, int n)
{
    __shared__ int sh[1024];
    __shared__ int carry_s;
    int tid = threadIdx.x;
    if (tid == 0) carry_s = 0;
    __syncthreads();
    for (int base = 0; base < n; base += 1024) {
        int i = base + tid;
        int v = (i < n) ? cnt[i] : 0;
        sh[tid] = v;
        __syncthreads();
        for (int offn = 1; offn < 1024; offn <<= 1) {
            int t = (tid >= offn) ? sh[tid - offn] : 0;
            __syncthreads();
            sh[tid] += t;
            __syncthreads();
        }
        int incl = sh[tid];
        if (i < n) rowptr[i] = carry_s + incl - v;   // exclusive
        __syncthreads();                              // all reads of carry_s done
        if (tid == 1023) carry_s += incl;             // chunk total
        __syncthreads();
    }
    if (tid == 0) rowptr[n] = carry_s;
}

__global__ void fill_kernel(const int* __restrict__ src, const int* __restrict__ dst,
                            const float* __restrict__ ew, const float* __restrict__ dinv,
                            const int* __restrict__ rowptr, int* __restrict__ cursor,
                            int* __restrict__ colb, float* __restrict__ valb, int nE)
{
    int i = blockIdx.x * blockDim.x + threadIdx.x;
    if (i < nE) {
        int s = src[i], d = dst[i];
        int pos = rowptr[d] + atomicAdd(&cursor[d], 1);
        colb[pos] = s;
        valb[pos] = dinv[s] * ew[i] * dinv[d];
    }
}

// ---------------------------------------------------------------- fp32 GEMM
// out[nrows x 128] = A[nrows x K] @ W[K x 128] (+bias)(relu)
// block: 256 thr, tile 128 rows x 128 cols, thread = 4 rows x 16 cols
// cols of thread: cg*4 + j*32 + jj  (conflict-free LDS: 8 cgs x 16B = 128B span)
template<bool RELU, bool BIAS>
__global__ __launch_bounds__(256) void gemm_kernel(
    const float* __restrict__ A, int lda, int K,
    const float* __restrict__ W, const float* __restrict__ bias,
    float* __restrict__ out, int ldo, int nrows)
{
    __shared__ float wl[64 * 128];   // 32 KB k-slab of W
    const int tid = threadIdx.x;
    const int cg  = tid & 7;
    const int rt  = tid >> 3;
    const int row0 = blockIdx.x * 128 + rt * 4;
    float acc[4][16];
    #pragma unroll
    for (int r = 0; r < 4; ++r)
        #pragma unroll
        for (int c = 0; c < 16; ++c) acc[r][c] = 0.f;
    bool rv[4];
    #pragma unroll
    for (int r = 0; r < 4; ++r) rv[r] = (row0 + r) < nrows;

    for (int ks = 0; ks < K; ks += 64) {
        __syncthreads();
        #pragma unroll
        for (int t = 0; t < 8; ++t) {
            int idx = (tid + t * 256) * 4;           // 8192 floats
            *(float4*)&wl[idx] = *(const float4*)&W[(size_t)ks * 128 + idx];
        }
        __syncthreads();
        for (int k = 0; k < 64; k += 4) {
            float4 a4[4];
            #pragma unroll
            for (int r = 0; r < 4; ++r)
                a4[r] = rv[r] ? *(const float4*)&A[(size_t)(row0 + r) * lda + ks + k]
                              : make_float4(0.f, 0.f, 0.f, 0.f);
            #pragma unroll
            for (int kk = 0; kk < 4; ++kk) {
                float4 wv[4];
                #pragma unroll
                for (int j = 0; j < 4; ++j)
                    wv[j] = *(const float4*)&wl[(k + kk) * 128 + cg * 4 + j * 32];
                #pragma unroll
                for (int r = 0; r < 4; ++r) {
                    float a = (&a4[r].x)[kk];
                    #pragma unroll
                    for (int j = 0; j < 4; ++j) {
                        acc[r][j*4+0] = fmaf(a, wv[j].x, acc[r][j*4+0]);
                        acc[r][j*4+1] = fmaf(a, wv[j].y, acc[r][j*4+1]);
                        acc[r][j*4+2] = fmaf(a, wv[j].z, acc[r][j*4+2]);
                        acc[r][j*4+3] = fmaf(a, wv[j].w, acc[r][j*4+3]);
                    }
                }
            }
        }
    }
    #pragma unroll
    for (int r = 0; r < 4; ++r) {
        if (!rv[r]) continue;
        #pragma unroll
        for (int j = 0; j < 4; ++j) {
            int c0 = cg * 4 + j * 32;
            float4 o;
            o.x = acc[r][j*4+0]; o.y = acc[r][j*4+1];
            o.z = acc[r][j*4+2]; o.w = acc[r][j*4+3];
            if (BIAS) { o.x += bias[c0+0]; o.y += bias[c0+1];
                        o.z += bias[c0+2]; o.w += bias[c0+3]; }
            if (RELU) { o.x = fmaxf(o.x,0.f); o.y = fmaxf(o.y,0.f);
                        o.z = fmaxf(o.z,0.f); o.w = fmaxf(o.w,0.f); }
            *(float4*)&out[(size_t)(row0 + r) * ldo + c0] = o;
        }
    }
}

// ------------------------------------------------------- sparse aggregation
// one wave per node; lane holds float2 of the 128 feats
__global__ __launch_bounds__(256) void agg_kernel(
    const float* __restrict__ xw, const int* __restrict__ rowptr,
    const int* __restrict__ colb, const float* __restrict__ valb,
    const float* __restrict__ dinv, const float* __restrict__ bias,
    float* __restrict__ out, int ldo, int n)
{
    int node = (int)((blockIdx.x * (size_t)blockDim.x + threadIdx.x) >> 6);
    int lane = threadIdx.x & 63;
    if (node >= n) return;
    float d  = dinv[node];
    float sw = d * d;                     // self-loop weight
    float2 xv = *(const float2*)&xw[(size_t)node * 128 + lane * 2];
    float ax = xv.x * sw, ay = xv.y * sw;
    int e0 = rowptr[node], e1 = rowptr[node + 1];
    for (int e = e0; e < e1; ++e) {
        int   c = colb[e];
        float v = valb[e];
        float2 g = *(const float2*)&xw[(size_t)c * 128 + lane * 2];
        ax = fmaf(v, g.x, ax);
        ay = fmaf(v, g.y, ay);
    }
    float2 b = *(const float2*)&bias[lane * 2];
    ax = fmaxf(ax + b.x, 0.f);
    ay = fmaxf(ay + b.y, 0.f);
    float2 o; o.x = ax; o.y = ay;
    *(float2*)&out[(size_t)node * ldo + lane * 2] = o;
}

// ---------------------------------------------------------------- pooling
__global__ void pool_kernel(const float* __restrict__ h, const int* __restrict__ batch,
                            float* __restrict__ z, int zoff, int n)
{
    int idx = blockIdx.x * blockDim.x + threadIdx.x;
    if (idx >= n * 128) return;
    int node = idx >> 7, f = idx & 127;
    atomicAdd(&z[(size_t)batch[node] * 384 + zoff + f], h[(size_t)node * 128 + f]);
}

// ---------------------------------------------------------------- head
__global__ __launch_bounds__(128) void head_kernel(
    const float* __restrict__ z,
    const float* __restrict__ g,  const float* __restrict__ be,
    const float* __restrict__ mu, const float* __restrict__ var,
    const float* __restrict__ w1, const float* __restrict__ b1,
    const float* __restrict__ w2, const float* __restrict__ b2,
    float* __restrict__ out)
{
    int gi = blockIdx.x;
    int t  = threadIdx.x;
    __shared__ float zs[384];
    __shared__ float h1[128];
    __shared__ float lg[10];
    for (int i = t; i < 384; i += 128) {
        float v = z[(size_t)gi * 384 + i];
        v = (v - mu[i]) * rsqrtf(var[i] + 1e-5f) * g[i] + be[i];
        zs[i] = v;
    }
    __syncthreads();
    float acc = b1[t];
    for (int k = 0; k < 384; ++k) acc = fmaf(zs[k], w1[(size_t)k * 128 + t], acc);
    h1[t] = fmaxf(acc, 0.f);
    __syncthreads();
    if (t < 10) {
        float a2 = b2[t];
        for (int k = 0; k < 128; ++k) a2 = fmaf(h1[k], w2[(size_t)k * 10 + t], a2);
        lg[t] = a2;
    }
    __syncthreads();
    if (t == 0) {
        float m = lg[0];
        for (int i = 1; i < 10; ++i) m = fmaxf(m, lg[i]);
        float e[10], s = 0.f;
        for (int i = 0; i < 10; ++i) { e[i] = expf(lg[i] - m); s += e[i]; }
        float inv = 1.f / s;
        for (int i = 0; i < 10; ++i) out[(size_t)gi * 10 + i] = e[i] * inv;
    }
}

// ---------------------------------------------------------------- launch
extern "C" void kernel_launch(void* const* d_in, const int* in_sizes, int n_in,
                              void* d_out, int out_size, void* d_ws, size_t ws_size,
                              hipStream_t stream)
{
    const float* x      = (const float*)d_in[0];
    const float* ea     = (const float*)d_in[1];
    const float* conv_w = (const float*)d_in[2];
    const float* conv_b = (const float*)d_in[3];
    const float* jk_w   = (const float*)d_in[4];
    const float* jk_b   = (const float*)d_in[5];
    const float* bn_g   = (const float*)d_in[6];
    const float* bn_b   = (const float*)d_in[7];
    const float* bn_m   = (const float*)d_in[8];
    const float* bn_v   = (const float*)d_in[9];
    const float* w1     = (const float*)d_in[10];
    const float* b1     = (const float*)d_in[11];
    const float* w2     = (const float*)d_in[12];
    const float* b2     = (const float*)d_in[13];
    const int*   eidx   = (const int*)d_in[14];
    const int*   batch  = (const int*)d_in[15];
    const int* srcv = eidx;
    const int* dstv = eidx + NE;
    float* out = (float*)d_out;

    char* ws = (char*)d_ws;
    size_t off = 0;
    auto alloc = [&](size_t b) { size_t o = off; off += (b + 511) & ~(size_t)511; return o; };
    // zero-init region first (one memset covers all four)
    float* deg    = (float*)(ws + alloc((size_t)NN * 4));
    int*   cnt    = (int*)  (ws + alloc((size_t)NN * 4));
    int*   cursor = (int*)  (ws + alloc((size_t)NN * 4));
    float* z      = (float*)(ws + alloc((size_t)NG * 384 * 4));
    size_t zero_bytes = off;
    float* dinv   = (float*)(ws + alloc((size_t)NN * 4));
    int*   rowptr = (int*)  (ws + alloc((size_t)(NN + 1) * 4));
    int*   colb   = (int*)  (ws + alloc((size_t)NE * 4));
    float* valb   = (float*)(ws + alloc((size_t)NE * 4));
    float* xw     = (float*)(ws + alloc((size_t)NN * 128 * 4));
    float* xs     = (float*)(ws + alloc((size_t)NN * 256 * 4));
    float* hout   = (float*)(ws + alloc((size_t)NN * 128 * 4));
    (void)ws_size; (void)in_sizes; (void)n_in; (void)out_size;

    hipMemsetAsync(d_ws, 0, zero_bytes, stream);

    const int EB = (NE + 255) / 256;
    hist_kernel<<<EB, 256, 0, stream>>>(dstv, ea, deg, cnt, NE);
    dinv_kernel<<<(NN + 255) / 256, 256, 0, stream>>>(deg, dinv, NN);
    scan_kernel<<<1, 1024, 0, stream>>>(cnt, rowptr, NN);
    fill_kernel<<<EB, 256, 0, stream>>>(srcv, dstv, ea, dinv, rowptr, cursor,
                                        colb, valb, NE);

    const int GB = (NN + 127) / 128;        // 391 gemm blocks
    const int AB = (NN * 64 + 255) / 256;   // agg: 1 wave/node
    const int PB = (NN * 128 + 255) / 256;

    const float* hin = x;
    int lda = 128;
    for (int l = 0; l < 3; ++l) {
        for (int k = 0; k < 2; ++k) {
            const float* Wc = conv_w + (size_t)(l * 2 + k) * 128 * 128;
            gemm_kernel<false, false><<<GB, 256, 0, stream>>>(
                hin, lda, 128, Wc, nullptr, xw, 128, NN);
            agg_kernel<<<AB, 256, 0, stream>>>(
                xw, rowptr, colb, valb, dinv, conv_b + (size_t)(l * 2 + k) * 128,
                xs + k * 128, 256, NN);
            hin = xs + k * 128;
            lda = 256;
        }
        gemm_kernel<true, true><<<GB, 256, 0, stream>>>(
            xs, 256, 256, jk_w + (size_t)l * 256 * 128, jk_b + (size_t)l * 128,
            hout, 128, NN);
        pool_kernel<<<PB, 256, 0, stream>>>(hout, batch, z, l * 128, NN);
        hin = hout;
        lda = 128;
    }
    head_kernel<<<NG, 128, 0, stream>>>(z, bn_g, bn_b, bn_m, bn_v,
                                        w1, b1, w2, b2, out);
}

// Round 2
// 1286.670 us; speedup vs baseline: 1.1122x; 1.1122x over previous
//
#include <hip/hip_runtime.h>

static constexpr int NN = 50000;   // nodes
static constexpr int NE = 800000;  // edges
static constexpr int NG = 512;     // graphs
// HID = 128, 3 blocks x 2 inner convs

// ---------------------------------------------------------------- histogram
__global__ void hist_kernel(const int* __restrict__ dst, const float* __restrict__ ew,
                            float* __restrict__ deg, int* __restrict__ cnt, int nE)
{
    int i = blockIdx.x * blockDim.x + threadIdx.x;
    if (i < nE) {
        int d = dst[i];
        atomicAdd(&deg[d], ew[i]);
        atomicAdd(&cnt[d], 1);
    }
}

__global__ void dinv_kernel(const float* __restrict__ deg, float* __restrict__ dinv, int n)
{
    int i = blockIdx.x * blockDim.x + threadIdx.x;
    if (i < n) dinv[i] = rsqrtf(deg[i] + 1.0f);
}

// ------------------------------------------------- two-level exclusive scan
// k1: per-block (256-elem) sums
__global__ __launch_bounds__(256) void scan_bsum_kernel(const int* __restrict__ cnt,
                                                        int* __restrict__ bsum, int n)
{
    __shared__ int wred[4];
    int i = blockIdx.x * 256 + threadIdx.x;
    int v = (i < n) ? cnt[i] : 0;
    #pragma unroll
    for (int o = 32; o > 0; o >>= 1) v += __shfl_down(v, o, 64);
    int wid = threadIdx.x >> 6;
    if ((threadIdx.x & 63) == 0) wred[wid] = v;
    __syncthreads();
    if (threadIdx.x == 0)
        bsum[blockIdx.x] = wred[0] + wred[1] + wred[2] + wred[3];
}

// k2: single block scans nbs (<=256) block sums -> exclusive boff, boff[nbs]=total
__global__ __launch_bounds__(256) void scan_boff_kernel(const int* __restrict__ bsum,
                                                        int* __restrict__ boff, int nbs)
{
    __shared__ int sh[256];
    int tid = threadIdx.x;
    int v = (tid < nbs) ? bsum[tid] : 0;
    sh[tid] = v;
    __syncthreads();
    #pragma unroll
    for (int o = 1; o < 256; o <<= 1) {
        int t = (tid >= o) ? sh[tid - o] : 0;
        __syncthreads();
        sh[tid] += t;
        __syncthreads();
    }
    if (tid < nbs) boff[tid] = sh[tid] - v;        // exclusive
    if (tid == 255) boff[nbs] = sh[255];           // total
}

// k3: per-block local exclusive scan + block offset -> rowptr
__global__ __launch_bounds__(256) void scan_final_kernel(const int* __restrict__ cnt,
                                                         const int* __restrict__ boff,
                                                         int* __restrict__ rowptr,
                                                         int n, int nbs)
{
    __shared__ int sh[256];
    int tid = threadIdx.x;
    int i = blockIdx.x * 256 + tid;
    int v = (i < n) ? cnt[i] : 0;
    sh[tid] = v;
    __syncthreads();
    #pragma unroll
    for (int o = 1; o < 256; o <<= 1) {
        int t = (tid >= o) ? sh[tid - o] : 0;
        __syncthreads();
        sh[tid] += t;
        __syncthreads();
    }
    if (i < n) rowptr[i] = boff[blockIdx.x] + sh[tid] - v;
    if (blockIdx.x == 0 && tid == 0) rowptr[n] = boff[nbs];
}

__global__ void fill_kernel(const int* __restrict__ src, const int* __restrict__ dst,
                            const float* __restrict__ ew, const float* __restrict__ dinv,
                            const int* __restrict__ rowptr, int* __restrict__ cursor,
                            int* __restrict__ colb, float* __restrict__ valb, int nE)
{
    int i = blockIdx.x * blockDim.x + threadIdx.x;
    if (i < nE) {
        int s = src[i], d = dst[i];
        int pos = rowptr[d] + atomicAdd(&cursor[d], 1);
        colb[pos] = s;
        valb[pos] = dinv[s] * ew[i] * dinv[d];
    }
}

// ---------------------------------------------------------------- fp32 GEMM
// out[nrows x 128] = A[nrows x K] @ W[K x 128] (+bias)(relu)
template<bool RELU, bool BIAS>
__global__ __launch_bounds__(256) void gemm_kernel(
    const float* __restrict__ A, int lda, int K,
    const float* __restrict__ W, const float* __restrict__ bias,
    float* __restrict__ out, int ldo, int nrows)
{
    __shared__ float wl[64 * 128];   // 32 KB k-slab of W
    const int tid = threadIdx.x;
    const int cg  = tid & 7;
    const int rt  = tid >> 3;
    const int row0 = blockIdx.x * 128 + rt * 4;
    float acc[4][16];
    #pragma unroll
    for (int r = 0; r < 4; ++r)
        #pragma unroll
        for (int c = 0; c < 16; ++c) acc[r][c] = 0.f;
    bool rv[4];
    #pragma unroll
    for (int r = 0; r < 4; ++r) rv[r] = (row0 + r) < nrows;

    for (int ks = 0; ks < K; ks += 64) {
        __syncthreads();
        #pragma unroll
        for (int t = 0; t < 8; ++t) {
            int idx = (tid + t * 256) * 4;           // 8192 floats
            *(float4*)&wl[idx] = *(const float4*)&W[(size_t)ks * 128 + idx];
        }
        __syncthreads();
        for (int k = 0; k < 64; k += 4) {
            float4 a4[4];
            #pragma unroll
            for (int r = 0; r < 4; ++r)
                a4[r] = rv[r] ? *(const float4*)&A[(size_t)(row0 + r) * lda + ks + k]
                              : make_float4(0.f, 0.f, 0.f, 0.f);
            #pragma unroll
            for (int kk = 0; kk < 4; ++kk) {
                float4 wv[4];
                #pragma unroll
                for (int j = 0; j < 4; ++j)
                    wv[j] = *(const float4*)&wl[(k + kk) * 128 + cg * 4 + j * 32];
                #pragma unroll
                for (int r = 0; r < 4; ++r) {
                    float a = (&a4[r].x)[kk];
                    #pragma unroll
                    for (int j = 0; j < 4; ++j) {
                        acc[r][j*4+0] = fmaf(a, wv[j].x, acc[r][j*4+0]);
                        acc[r][j*4+1] = fmaf(a, wv[j].y, acc[r][j*4+1]);
                        acc[r][j*4+2] = fmaf(a, wv[j].z, acc[r][j*4+2]);
                        acc[r][j*4+3] = fmaf(a, wv[j].w, acc[r][j*4+3]);
                    }
                }
            }
        }
    }
    #pragma unroll
    for (int r = 0; r < 4; ++r) {
        if (!rv[r]) continue;
        #pragma unroll
        for (int j = 0; j < 4; ++j) {
            int c0 = cg * 4 + j * 32;
            float4 o;
            o.x = acc[r][j*4+0]; o.y = acc[r][j*4+1];
            o.z = acc[r][j*4+2]; o.w = acc[r][j*4+3];
            if (BIAS) { o.x += bias[c0+0]; o.y += bias[c0+1];
                        o.z += bias[c0+2]; o.w += bias[c0+3]; }
            if (RELU) { o.x = fmaxf(o.x,0.f); o.y = fmaxf(o.y,0.f);
                        o.z = fmaxf(o.z,0.f); o.w = fmaxf(o.w,0.f); }
            *(float4*)&out[(size_t)(row0 + r) * ldo + c0] = o;
        }
    }
}

// ------------------------------------------------------- sparse aggregation
// one wave per node; lane holds float2 of the 128 feats
__global__ __launch_bounds__(256) void agg_kernel(
    const float* __restrict__ xw, const int* __restrict__ rowptr,
    const int* __restrict__ colb, const float* __restrict__ valb,
    const float* __restrict__ dinv, const float* __restrict__ bias,
    float* __restrict__ out, int ldo, int n)
{
    int node = (int)((blockIdx.x * (size_t)blockDim.x + threadIdx.x) >> 6);
    int lane = threadIdx.x & 63;
    if (node >= n) return;
    float d  = dinv[node];
    float sw = d * d;                     // self-loop weight
    float2 xv = *(const float2*)&xw[(size_t)node * 128 + lane * 2];
    float ax = xv.x * sw, ay = xv.y * sw;
    int e0 = rowptr[node], e1 = rowptr[node + 1];
    for (int e = e0; e < e1; ++e) {
        int   c = colb[e];
        float v = valb[e];
        float2 g = *(const float2*)&xw[(size_t)c * 128 + lane * 2];
        ax = fmaf(v, g.x, ax);
        ay = fmaf(v, g.y, ay);
    }
    float2 b = *(const float2*)&bias[lane * 2];
    ax = fmaxf(ax + b.x, 0.f);
    ay = fmaxf(ay + b.y, 0.f);
    float2 o; o.x = ax; o.y = ay;
    *(float2*)&out[(size_t)node * ldo + lane * 2] = o;
}

// ---------------------------------------------------------------- pooling
// batch is sorted: run-length segmented reduction, ~1 atomic per boundary.
// blockDim = 128 (thread = feature), each block handles NPP consecutive nodes.
static constexpr int NPP = 32;
__global__ __launch_bounds__(128) void pool_kernel(
    const float* __restrict__ h, const int* __restrict__ batch,
    float* __restrict__ z, int zoff, int n)
{
    int f  = threadIdx.x;
    int n0 = blockIdx.x * NPP;
    if (n0 >= n) return;
    int nend = n0 + NPP; if (nend > n) nend = n;
    int cur = batch[n0];
    float acc = 0.f;
    for (int node = n0; node < nend; ++node) {
        int b = batch[node];                  // wave-uniform
        if (b != cur) {
            atomicAdd(&z[(size_t)cur * 384 + zoff + f], acc);
            acc = 0.f; cur = b;
        }
        acc += h[(size_t)node * 128 + f];
    }
    atomicAdd(&z[(size_t)cur * 384 + zoff + f], acc);
}

// ---------------------------------------------------------------- head
__global__ __launch_bounds__(128) void head_kernel(
    const float* __restrict__ z,
    const float* __restrict__ g,  const float* __restrict__ be,
    const float* __restrict__ mu, const float* __restrict__ var,
    const float* __restrict__ w1, const float* __restrict__ b1,
    const float* __restrict__ w2, const float* __restrict__ b2,
    float* __restrict__ out)
{
    int gi = blockIdx.x;
    int t  = threadIdx.x;
    __shared__ float zs[384];
    __shared__ float h1[128];
    __shared__ float lg[10];
    for (int i = t; i < 384; i += 128) {
        float v = z[(size_t)gi * 384 + i];
        v = (v - mu[i]) * rsqrtf(var[i] + 1e-5f) * g[i] + be[i];
        zs[i] = v;
    }
    __syncthreads();
    float acc = b1[t];
    for (int k = 0; k < 384; ++k) acc = fmaf(zs[k], w1[(size_t)k * 128 + t], acc);
    h1[t] = fmaxf(acc, 0.f);
    __syncthreads();
    if (t < 10) {
        float a2 = b2[t];
        for (int k = 0; k < 128; ++k) a2 = fmaf(h1[k], w2[(size_t)k * 10 + t], a2);
        lg[t] = a2;
    }
    __syncthreads();
    if (t == 0) {
        float m = lg[0];
        for (int i = 1; i < 10; ++i) m = fmaxf(m, lg[i]);
        float e[10], s = 0.f;
        for (int i = 0; i < 10; ++i) { e[i] = expf(lg[i] - m); s += e[i]; }
        float inv = 1.f / s;
        for (int i = 0; i < 10; ++i) out[(size_t)gi * 10 + i] = e[i] * inv;
    }
}

// ---------------------------------------------------------------- launch
extern "C" void kernel_launch(void* const* d_in, const int* in_sizes, int n_in,
                              void* d_out, int out_size, void* d_ws, size_t ws_size,
                              hipStream_t stream)
{
    const float* x      = (const float*)d_in[0];
    const float* ea     = (const float*)d_in[1];
    const float* conv_w = (const float*)d_in[2];
    const float* conv_b = (const float*)d_in[3];
    const float* jk_w   = (const float*)d_in[4];
    const float* jk_b   = (const float*)d_in[5];
    const float* bn_g   = (const float*)d_in[6];
    const float* bn_b   = (const float*)d_in[7];
    const float* bn_m   = (const float*)d_in[8];
    const float* bn_v   = (const float*)d_in[9];
    const float* w1     = (const float*)d_in[10];
    const float* b1     = (const float*)d_in[11];
    const float* w2     = (const float*)d_in[12];
    const float* b2     = (const float*)d_in[13];
    const int*   eidx   = (const int*)d_in[14];
    const int*   batch  = (const int*)d_in[15];
    const int* srcv = eidx;
    const int* dstv = eidx + NE;
    float* out = (float*)d_out;

    char* ws = (char*)d_ws;
    size_t off = 0;
    auto alloc = [&](size_t b) { size_t o = off; off += (b + 511) & ~(size_t)511; return o; };
    // zero-init region first (one memset covers all four)
    float* deg    = (float*)(ws + alloc((size_t)NN * 4));
    int*   cnt    = (int*)  (ws + alloc((size_t)NN * 4));
    int*   cursor = (int*)  (ws + alloc((size_t)NN * 4));
    float* z      = (float*)(ws + alloc((size_t)NG * 384 * 4));
    size_t zero_bytes = off;
    float* dinv   = (float*)(ws + alloc((size_t)NN * 4));
    int*   rowptr = (int*)  (ws + alloc((size_t)(NN + 1) * 4));
    int*   colb   = (int*)  (ws + alloc((size_t)NE * 4));
    float* valb   = (float*)(ws + alloc((size_t)NE * 4));
    float* xw     = (float*)(ws + alloc((size_t)NN * 128 * 4));
    float* xs     = (float*)(ws + alloc((size_t)NN * 256 * 4));
    float* hout   = (float*)(ws + alloc((size_t)NN * 128 * 4));
    int*   bsum   = (int*)  (ws + alloc((size_t)256 * 4));
    int*   boff   = (int*)  (ws + alloc((size_t)257 * 4));
    (void)ws_size; (void)in_sizes; (void)n_in; (void)out_size;

    hipMemsetAsync(d_ws, 0, zero_bytes, stream);

    const int EB  = (NE + 255) / 256;
    const int NB  = (NN + 255) / 256;       // 196 scan blocks
    hist_kernel<<<EB, 256, 0, stream>>>(dstv, ea, deg, cnt, NE);
    dinv_kernel<<<NB, 256, 0, stream>>>(deg, dinv, NN);
    scan_bsum_kernel<<<NB, 256, 0, stream>>>(cnt, bsum, NN);
    scan_boff_kernel<<<1, 256, 0, stream>>>(bsum, boff, NB);
    scan_final_kernel<<<NB, 256, 0, stream>>>(cnt, boff, rowptr, NN, NB);
    fill_kernel<<<EB, 256, 0, stream>>>(srcv, dstv, ea, dinv, rowptr, cursor,
                                        colb, valb, NE);

    const int GB = (NN + 127) / 128;        // 391 gemm blocks
    const int AB = (NN * 64 + 255) / 256;   // agg: 1 wave/node
    const int PB = (NN + NPP - 1) / NPP;    // pool blocks

    const float* hin = x;
    int lda = 128;
    for (int l = 0; l < 3; ++l) {
        for (int k = 0; k < 2; ++k) {
            const float* Wc = conv_w + (size_t)(l * 2 + k) * 128 * 128;
            gemm_kernel<false, false><<<GB, 256, 0, stream>>>(
                hin, lda, 128, Wc, nullptr, xw, 128, NN);
            agg_kernel<<<AB, 256, 0, stream>>>(
                xw, rowptr, colb, valb, dinv, conv_b + (size_t)(l * 2 + k) * 128,
                xs + k * 128, 256, NN);
            hin = xs + k * 128;
            lda = 256;
        }
        gemm_kernel<true, true><<<GB, 256, 0, stream>>>(
            xs, 256, 256, jk_w + (size_t)l * 256 * 128, jk_b + (size_t)l * 128,
            hout, 128, NN);
        pool_kernel<<<PB, 128, 0, stream>>>(hout, batch, z, l * 128, NN);
        hin = hout;
        lda = 128;
    }
    head_kernel<<<NG, 128, 0, stream>>>(z, bn_g, bn_b, bn_m, bn_v,
                                        w1, b1, w2, b2, out);
}

// Round 3
// 994.870 us; speedup vs baseline: 1.4383x; 1.2933x over previous
//
#include <hip/hip_runtime.h>

static constexpr int NN = 50000;   // nodes
static constexpr int NE = 800000;  // edges
static constexpr int NG = 512;     // graphs

typedef unsigned int uint;

__device__ inline uint bfbits(float f) {
    uint u = __float_as_uint(f);
    return (u + 0x7fffu + ((u >> 16) & 1u)) >> 16;   // RNE to bf16
}

// ---------------------------------------------------------------- histogram
__global__ void hist_kernel(const int* __restrict__ dst, const float* __restrict__ ew,
                            float* __restrict__ deg, int* __restrict__ cnt, int nE)
{
    int i = blockIdx.x * blockDim.x + threadIdx.x;
    if (i < nE) {
        int d = dst[i];
        atomicAdd(&deg[d], ew[i]);
        atomicAdd(&cnt[d], 1);
    }
}

__global__ void dinv_kernel(const float* __restrict__ deg, float* __restrict__ dinv, int n)
{
    int i = blockIdx.x * blockDim.x + threadIdx.x;
    if (i < n) dinv[i] = rsqrtf(deg[i] + 1.0f);
}

// ------------------------------------------------- two-level exclusive scan
__global__ __launch_bounds__(256) void scan_bsum_kernel(const int* __restrict__ cnt,
                                                        int* __restrict__ bsum, int n)
{
    __shared__ int wred[4];
    int i = blockIdx.x * 256 + threadIdx.x;
    int v = (i < n) ? cnt[i] : 0;
    #pragma unroll
    for (int o = 32; o > 0; o >>= 1) v += __shfl_down(v, o, 64);
    int wid = threadIdx.x >> 6;
    if ((threadIdx.x & 63) == 0) wred[wid] = v;
    __syncthreads();
    if (threadIdx.x == 0)
        bsum[blockIdx.x] = wred[0] + wred[1] + wred[2] + wred[3];
}

__global__ __launch_bounds__(256) void scan_boff_kernel(const int* __restrict__ bsum,
                                                        int* __restrict__ boff, int nbs)
{
    __shared__ int sh[256];
    int tid = threadIdx.x;
    int v = (tid < nbs) ? bsum[tid] : 0;
    sh[tid] = v;
    __syncthreads();
    #pragma unroll
    for (int o = 1; o < 256; o <<= 1) {
        int t = (tid >= o) ? sh[tid - o] : 0;
        __syncthreads();
        sh[tid] += t;
        __syncthreads();
    }
    if (tid < nbs) boff[tid] = sh[tid] - v;        // exclusive
    if (tid == 255) boff[nbs] = sh[255];           // total
}

__global__ __launch_bounds__(256) void scan_final_kernel(const int* __restrict__ cnt,
                                                         const int* __restrict__ boff,
                                                         int* __restrict__ rowptr,
                                                         int n, int nbs)
{
    __shared__ int sh[256];
    int tid = threadIdx.x;
    int i = blockIdx.x * 256 + tid;
    int v = (i < n) ? cnt[i] : 0;
    sh[tid] = v;
    __syncthreads();
    #pragma unroll
    for (int o = 1; o < 256; o <<= 1) {
        int t = (tid >= o) ? sh[tid - o] : 0;
        __syncthreads();
        sh[tid] += t;
        __syncthreads();
    }
    if (i < n) rowptr[i] = boff[blockIdx.x] + sh[tid] - v;
    if (blockIdx.x == 0 && tid == 0) rowptr[n] = boff[nbs];
}

__global__ void fill_kernel(const int* __restrict__ src, const int* __restrict__ dst,
                            const float* __restrict__ ew, const float* __restrict__ dinv,
                            const int* __restrict__ rowptr, int* __restrict__ cursor,
                            int* __restrict__ colb, float* __restrict__ valb, int nE)
{
    int i = blockIdx.x * blockDim.x + threadIdx.x;
    if (i < nE) {
        int s = src[i], d = dst[i];
        int pos = rowptr[d] + atomicAdd(&cursor[d], 1);
        colb[pos] = s;
        valb[pos] = dinv[s] * ew[i] * dinv[d];
    }
}

// ---------------------------------------------------------------- fp32 GEMM
// out[nrows x 128] = A[nrows x K] @ W[K x 128] (+bias)(relu)(+bf16 copy)
// 256 thr, tile 64 rows x 128 cols, thread = 2 rows x 16 cols
template<bool RELU, bool BIAS, bool WBF16>
__global__ __launch_bounds__(256) void gemm_kernel(
    const float* __restrict__ A, int lda, int K,
    const float* __restrict__ W, const float* __restrict__ bias,
    float* __restrict__ out, int ldo, uint* __restrict__ outb, int nrows)
{
    __shared__ float wl[64 * 128];   // 32 KB k-slab of W
    const int tid = threadIdx.x;
    const int cg  = tid & 7;
    const int rt  = tid >> 3;                 // 0..31
    const int row0 = blockIdx.x * 64 + rt * 2;
    float acc[2][16];
    #pragma unroll
    for (int r = 0; r < 2; ++r)
        #pragma unroll
        for (int c = 0; c < 16; ++c) acc[r][c] = 0.f;
    bool rv[2];
    rv[0] = row0 < nrows;
    rv[1] = row0 + 1 < nrows;

    for (int ks = 0; ks < K; ks += 64) {
        __syncthreads();
        #pragma unroll
        for (int t = 0; t < 8; ++t) {
            int idx = (tid + t * 256) * 4;           // 8192 floats
            *(float4*)&wl[idx] = *(const float4*)&W[(size_t)ks * 128 + idx];
        }
        __syncthreads();
        for (int k = 0; k < 64; k += 4) {
            float4 a4[2];
            #pragma unroll
            for (int r = 0; r < 2; ++r)
                a4[r] = rv[r] ? *(const float4*)&A[(size_t)(row0 + r) * lda + ks + k]
                              : make_float4(0.f, 0.f, 0.f, 0.f);
            #pragma unroll
            for (int kk = 0; kk < 4; ++kk) {
                float4 wv[4];
                #pragma unroll
                for (int j = 0; j < 4; ++j)
                    wv[j] = *(const float4*)&wl[(k + kk) * 128 + cg * 4 + j * 32];
                #pragma unroll
                for (int r = 0; r < 2; ++r) {
                    float a = (&a4[r].x)[kk];
                    #pragma unroll
                    for (int j = 0; j < 4; ++j) {
                        acc[r][j*4+0] = fmaf(a, wv[j].x, acc[r][j*4+0]);
                        acc[r][j*4+1] = fmaf(a, wv[j].y, acc[r][j*4+1]);
                        acc[r][j*4+2] = fmaf(a, wv[j].z, acc[r][j*4+2]);
                        acc[r][j*4+3] = fmaf(a, wv[j].w, acc[r][j*4+3]);
                    }
                }
            }
        }
    }
    #pragma unroll
    for (int r = 0; r < 2; ++r) {
        if (!rv[r]) continue;
        #pragma unroll
        for (int j = 0; j < 4; ++j) {
            int c0 = cg * 4 + j * 32;
            float4 o;
            o.x = acc[r][j*4+0]; o.y = acc[r][j*4+1];
            o.z = acc[r][j*4+2]; o.w = acc[r][j*4+3];
            if (BIAS) { o.x += bias[c0+0]; o.y += bias[c0+1];
                        o.z += bias[c0+2]; o.w += bias[c0+3]; }
            if (RELU) { o.x = fmaxf(o.x,0.f); o.y = fmaxf(o.y,0.f);
                        o.z = fmaxf(o.z,0.f); o.w = fmaxf(o.w,0.f); }
            *(float4*)&out[(size_t)(row0 + r) * ldo + c0] = o;
            if (WBF16) {
                uint2 p;
                p.x = bfbits(o.x) | (bfbits(o.y) << 16);
                p.y = bfbits(o.z) | (bfbits(o.w) << 16);
                *(uint2*)&outb[(size_t)(row0 + r) * 64 + (c0 >> 1)] = p;
            }
        }
    }
}

// ------------------------------------------------------- sparse aggregation
// one wave per node; lane holds 2 feats. Gather from bf16 copy (256B/row);
// self-loop from fp32 xw. Accumulate fp32.
__global__ __launch_bounds__(256) void agg_kernel(
    const float* __restrict__ xw, const uint* __restrict__ xwb,
    const int* __restrict__ rowptr,
    const int* __restrict__ colb, const float* __restrict__ valb,
    const float* __restrict__ dinv, const float* __restrict__ bias,
    float* __restrict__ out, int ldo, int n)
{
    int node = (int)((blockIdx.x * (size_t)blockDim.x + threadIdx.x) >> 6);
    int lane = threadIdx.x & 63;
    if (node >= n) return;
    float d  = dinv[node];
    float sw = d * d;                     // self-loop weight
    float2 xv = *(const float2*)&xw[(size_t)node * 128 + lane * 2];
    float ax = xv.x * sw, ay = xv.y * sw;
    int e0 = rowptr[node], e1 = rowptr[node + 1];
    int e = e0;
    for (; e + 2 <= e1; e += 2) {
        int   c0 = colb[e],     c1 = colb[e + 1];
        float v0 = valb[e],     v1 = valb[e + 1];
        uint  g0 = xwb[(size_t)c0 * 64 + lane];
        uint  g1 = xwb[(size_t)c1 * 64 + lane];
        ax = fmaf(v0, __uint_as_float(g0 << 16), ax);
        ay = fmaf(v0, __uint_as_float(g0 & 0xffff0000u), ay);
        ax = fmaf(v1, __uint_as_float(g1 << 16), ax);
        ay = fmaf(v1, __uint_as_float(g1 & 0xffff0000u), ay);
    }
    if (e < e1) {
        int   c = colb[e];
        float v = valb[e];
        uint  g = xwb[(size_t)c * 64 + lane];
        ax = fmaf(v, __uint_as_float(g << 16), ax);
        ay = fmaf(v, __uint_as_float(g & 0xffff0000u), ay);
    }
    float2 b = *(const float2*)&bias[lane * 2];
    ax = fmaxf(ax + b.x, 0.f);
    ay = fmaxf(ay + b.y, 0.f);
    float2 o; o.x = ax; o.y = ay;
    *(float2*)&out[(size_t)node * ldo + lane * 2] = o;
}

// ---------------------------------------------------------------- pooling
// batch is sorted: run-length segmented reduction, ~1 atomic per boundary.
static constexpr int NPP = 32;
__global__ __launch_bounds__(128) void pool_kernel(
    const float* __restrict__ h, const int* __restrict__ batch,
    float* __restrict__ z, int zoff, int n)
{
    int f  = threadIdx.x;
    int n0 = blockIdx.x * NPP;
    if (n0 >= n) return;
    int nend = n0 + NPP; if (nend > n) nend = n;
    int cur = batch[n0];
    float acc = 0.f;
    for (int node = n0; node < nend; ++node) {
        int b = batch[node];                  // wave-uniform
        if (b != cur) {
            atomicAdd(&z[(size_t)cur * 384 + zoff + f], acc);
            acc = 0.f; cur = b;
        }
        acc += h[(size_t)node * 128 + f];
    }
    atomicAdd(&z[(size_t)cur * 384 + zoff + f], acc);
}

// ---------------------------------------------------------------- head
__global__ __launch_bounds__(128) void head_kernel(
    const float* __restrict__ z,
    const float* __restrict__ g,  const float* __restrict__ be,
    const float* __restrict__ mu, const float* __restrict__ var,
    const float* __restrict__ w1, const float* __restrict__ b1,
    const float* __restrict__ w2, const float* __restrict__ b2,
    float* __restrict__ out)
{
    int gi = blockIdx.x;
    int t  = threadIdx.x;
    __shared__ float zs[384];
    __shared__ float h1[128];
    __shared__ float lg[10];
    for (int i = t; i < 384; i += 128) {
        float v = z[(size_t)gi * 384 + i];
        v = (v - mu[i]) * rsqrtf(var[i] + 1e-5f) * g[i] + be[i];
        zs[i] = v;
    }
    __syncthreads();
    float acc = b1[t];
    for (int k = 0; k < 384; ++k) acc = fmaf(zs[k], w1[(size_t)k * 128 + t], acc);
    h1[t] = fmaxf(acc, 0.f);
    __syncthreads();
    if (t < 10) {
        float a2 = b2[t];
        for (int k = 0; k < 128; ++k) a2 = fmaf(h1[k], w2[(size_t)k * 10 + t], a2);
        lg[t] = a2;
    }
    __syncthreads();
    if (t == 0) {
        float m = lg[0];
        for (int i = 1; i < 10; ++i) m = fmaxf(m, lg[i]);
        float e[10], s = 0.f;
        for (int i = 0; i < 10; ++i) { e[i] = expf(lg[i] - m); s += e[i]; }
        float inv = 1.f / s;
        for (int i = 0; i < 10; ++i) out[(size_t)gi * 10 + i] = e[i] * inv;
    }
}

// ---------------------------------------------------------------- launch
extern "C" void kernel_launch(void* const* d_in, const int* in_sizes, int n_in,
                              void* d_out, int out_size, void* d_ws, size_t ws_size,
                              hipStream_t stream)
{
    const float* x      = (const float*)d_in[0];
    const float* ea     = (const float*)d_in[1];
    const float* conv_w = (const float*)d_in[2];
    const float* conv_b = (const float*)d_in[3];
    const float* jk_w   = (const float*)d_in[4];
    const float* jk_b   = (const float*)d_in[5];
    const float* bn_g   = (const float*)d_in[6];
    const float* bn_b   = (const float*)d_in[7];
    const float* bn_m   = (const float*)d_in[8];
    const float* bn_v   = (const float*)d_in[9];
    const float* w1     = (const float*)d_in[10];
    const float* b1     = (const float*)d_in[11];
    const float* w2     = (const float*)d_in[12];
    const float* b2     = (const float*)d_in[13];
    const int*   eidx   = (const int*)d_in[14];
    const int*   batch  = (const int*)d_in[15];
    const int* srcv = eidx;
    const int* dstv = eidx + NE;
    float* out = (float*)d_out;

    char* ws = (char*)d_ws;
    size_t off = 0;
    auto alloc = [&](size_t b) { size_t o = off; off += (b + 511) & ~(size_t)511; return o; };
    // zero-init region first (one memset covers all)
    float* deg    = (float*)(ws + alloc((size_t)NN * 4));
    int*   cnt    = (int*)  (ws + alloc((size_t)NN * 4));
    int*   cursor = (int*)  (ws + alloc((size_t)NN * 4));
    float* z      = (float*)(ws + alloc((size_t)NG * 384 * 4));
    size_t zero_bytes = off;
    float* dinv   = (float*)(ws + alloc((size_t)NN * 4));
    int*   rowptr = (int*)  (ws + alloc((size_t)(NN + 1) * 4));
    int*   colb   = (int*)  (ws + alloc((size_t)NE * 4));
    float* valb   = (float*)(ws + alloc((size_t)NE * 4));
    float* xw     = (float*)(ws + alloc((size_t)NN * 128 * 4));
    uint*  xwb    = (uint*) (ws + alloc((size_t)NN * 64 * 4));
    float* xs     = (float*)(ws + alloc((size_t)NN * 256 * 4));
    float* hout   = (float*)(ws + alloc((size_t)NN * 128 * 4));
    int*   bsum   = (int*)  (ws + alloc((size_t)256 * 4));
    int*   boff   = (int*)  (ws + alloc((size_t)257 * 4));
    (void)ws_size; (void)in_sizes; (void)n_in; (void)out_size;

    hipMemsetAsync(d_ws, 0, zero_bytes, stream);

    const int EB  = (NE + 255) / 256;
    const int NB  = (NN + 255) / 256;
    hist_kernel<<<EB, 256, 0, stream>>>(dstv, ea, deg, cnt, NE);
    dinv_kernel<<<NB, 256, 0, stream>>>(deg, dinv, NN);
    scan_bsum_kernel<<<NB, 256, 0, stream>>>(cnt, bsum, NN);
    scan_boff_kernel<<<1, 256, 0, stream>>>(bsum, boff, NB);
    scan_final_kernel<<<NB, 256, 0, stream>>>(cnt, boff, rowptr, NN, NB);
    fill_kernel<<<EB, 256, 0, stream>>>(srcv, dstv, ea, dinv, rowptr, cursor,
                                        colb, valb, NE);

    const int GB = (NN + 63) / 64;          // 782 gemm blocks
    const int AB = (NN * 64 + 255) / 256;   // agg: 1 wave/node
    const int PB = (NN + NPP - 1) / NPP;    // pool blocks

    const float* hin = x;
    int lda = 128;
    for (int l = 0; l < 3; ++l) {
        for (int k = 0; k < 2; ++k) {
            const float* Wc = conv_w + (size_t)(l * 2 + k) * 128 * 128;
            gemm_kernel<false, false, true><<<GB, 256, 0, stream>>>(
                hin, lda, 128, Wc, nullptr, xw, 128, xwb, NN);
            agg_kernel<<<AB, 256, 0, stream>>>(
                xw, xwb, rowptr, colb, valb, dinv,
                conv_b + (size_t)(l * 2 + k) * 128, xs + k * 128, 256, NN);
            hin = xs + k * 128;
            lda = 256;
        }
        gemm_kernel<true, true, false><<<GB, 256, 0, stream>>>(
            xs, 256, 256, jk_w + (size_t)l * 256 * 128, jk_b + (size_t)l * 128,
            hout, 128, nullptr, NN);
        pool_kernel<<<PB, 128, 0, stream>>>(hout, batch, z, l * 128, NN);
        hin = hout;
        lda = 128;
    }
    head_kernel<<<NG, 128, 0, stream>>>(z, bn_g, bn_b, bn_m, bn_v,
                                        w1, b1, w2, b2, out);
}

// Round 4
// 725.327 us; speedup vs baseline: 1.9729x; 1.3716x over previous
//
#include <hip/hip_runtime.h>

static constexpr int NN = 50000;   // nodes
static constexpr int NE = 800000;  // edges
static constexpr int NG = 512;     // graphs

typedef unsigned int uint;
typedef unsigned short ushort;
typedef unsigned long long u64;
typedef __attribute__((ext_vector_type(8))) short short8;
typedef __attribute__((ext_vector_type(4))) float f32x4;

__device__ inline uint bfbits(float f) {
    uint u = __float_as_uint(f);
    return (u + 0x7fffu + ((u >> 16) & 1u)) >> 16;   // RNE to bf16
}
__device__ inline float bflo(uint g) { return __uint_as_float(g << 16); }
__device__ inline float bfhi(uint g) { return __uint_as_float(g & 0xffff0000u); }
__device__ inline float bf2f(ushort s) { return __uint_as_float(((uint)s) << 16); }

// ---------------------------------------------------------------- histogram
__global__ void hist_kernel(const int* __restrict__ dst, const float* __restrict__ ew,
                            u64* __restrict__ pk, int nE)
{
    int i = blockIdx.x * blockDim.x + threadIdx.x;
    if (i < nE) {
        int d = dst[i];
        u64 v = (1ULL << 40) + (u64)(ew[i] * 16777216.0f + 0.5f);
        atomicAdd(&pk[d], v);
    }
}

__global__ void dinv_kernel(const u64* __restrict__ pk, float* __restrict__ dinv, int n)
{
    int i = blockIdx.x * blockDim.x + threadIdx.x;
    if (i < n) {
        float deg = (float)(pk[i] & 0xFFFFFFFFFFULL) * (1.0f / 16777216.0f) + 1.0f;
        dinv[i] = rsqrtf(deg);
    }
}

// ------------------------------------------------- two-level exclusive scan
__global__ __launch_bounds__(256) void scan_bsum_kernel(const u64* __restrict__ pk,
                                                        int* __restrict__ bsum, int n)
{
    __shared__ int wred[4];
    int i = blockIdx.x * 256 + threadIdx.x;
    int v = (i < n) ? (int)(pk[i] >> 40) : 0;
    #pragma unroll
    for (int o = 32; o > 0; o >>= 1) v += __shfl_down(v, o, 64);
    int wid = threadIdx.x >> 6;
    if ((threadIdx.x & 63) == 0) wred[wid] = v;
    __syncthreads();
    if (threadIdx.x == 0)
        bsum[blockIdx.x] = wred[0] + wred[1] + wred[2] + wred[3];
}

__global__ __launch_bounds__(256) void scan_boff_kernel(const int* __restrict__ bsum,
                                                        int* __restrict__ boff, int nbs)
{
    __shared__ int sh[256];
    int tid = threadIdx.x;
    int v = (tid < nbs) ? bsum[tid] : 0;
    sh[tid] = v;
    __syncthreads();
    #pragma unroll
    for (int o = 1; o < 256; o <<= 1) {
        int t = (tid >= o) ? sh[tid - o] : 0;
        __syncthreads();
        sh[tid] += t;
        __syncthreads();
    }
    if (tid < nbs) boff[tid] = sh[tid] - v;        // exclusive
    if (tid == 255) boff[nbs] = sh[255];           // total
}

__global__ __launch_bounds__(256) void scan_final_kernel(const u64* __restrict__ pk,
                                                         const int* __restrict__ boff,
                                                         int* __restrict__ rowptr,
                                                         int n, int nbs)
{
    __shared__ int sh[256];
    int tid = threadIdx.x;
    int i = blockIdx.x * 256 + tid;
    int v = (i < n) ? (int)(pk[i] >> 40) : 0;
    sh[tid] = v;
    __syncthreads();
    #pragma unroll
    for (int o = 1; o < 256; o <<= 1) {
        int t = (tid >= o) ? sh[tid - o] : 0;
        __syncthreads();
        sh[tid] += t;
        __syncthreads();
    }
    if (i < n) rowptr[i] = boff[blockIdx.x] + sh[tid] - v;
    if (blockIdx.x == 0 && tid == 0) rowptr[n] = boff[nbs];
}

__global__ void fill_kernel(const int* __restrict__ src, const int* __restrict__ dst,
                            const float* __restrict__ ew, const float* __restrict__ dinv,
                            const int* __restrict__ rowptr, int* __restrict__ cursor,
                            uint2* __restrict__ ecv, int nE)
{
    int i = blockIdx.x * blockDim.x + threadIdx.x;
    if (i < nE) {
        int s = src[i], d = dst[i];
        int pos = rowptr[d] + atomicAdd(&cursor[d], 1);
        uint2 cv;
        cv.x = (uint)s;
        cv.y = __float_as_uint(dinv[s] * ew[i] * dinv[d]);
        ecv[pos] = cv;
    }
}

// ---------------------------------------------------------------- x -> bf16
__global__ void cvtx_kernel(const float* __restrict__ x, ushort* __restrict__ xb, int n)
{
    int i = (blockIdx.x * blockDim.x + threadIdx.x) * 4;
    if (i < n) {
        float4 v = *(const float4*)&x[i];
        uint2 p;
        p.x = bfbits(v.x) | (bfbits(v.y) << 16);
        p.y = bfbits(v.z) | (bfbits(v.w) << 16);
        *(uint2*)&xb[i] = p;
    }
}

// ------------------------------------------- W -> bf16 fragment layout
// dst idx = ((j*nt + t)*64 + lane)*8 + e  <-  src[k*128 + col]
// k = t*32 + (lane>>4)*8 + e, col = j*16 + (lane&15), nt = K/32
__global__ void wfrag_kernel(const float* __restrict__ src, ushort* __restrict__ dst,
                             int K, int wstride_src, int wstride_dst)
{
    int wid = blockIdx.y;
    const float* s = src + (size_t)wid * wstride_src;
    ushort* d = dst + (size_t)wid * wstride_dst;
    int i = blockIdx.x * 256 + threadIdx.x;          // < K*128
    int e = i & 7;
    int lane = (i >> 3) & 63;
    int rest = i >> 9;
    int nt = K >> 5;
    int t = rest % nt;
    int j = rest / nt;
    int k = t * 32 + (lane >> 4) * 8 + e;
    int col = j * 16 + (lane & 15);
    d[i] = (ushort)bfbits(s[(size_t)k * 128 + col]);
}

// ---------------------------------------------------------------- MFMA GEMM
// outb[nrows x 128] (bf16) = Ab[nrows x lda][0:K] (bf16) @ W-frag, fp32 acc
template<bool RELU, bool BIAS>
__global__ __launch_bounds__(256) void gemm_mfma_kernel(
    const ushort* __restrict__ Ab, int K, int lda,
    const ushort* __restrict__ Wb, const float* __restrict__ bias,
    ushort* __restrict__ outb, int nrows)
{
    const int wid  = threadIdx.x >> 6;
    const int lane = threadIdx.x & 63;
    const int row0 = blockIdx.x * 64 + wid * 16;
    const int c    = lane & 15;
    const int kg   = lane >> 4;
    int arow = row0 + c;
    if (arow >= nrows) arow = nrows - 1;             // clamp; stores guarded
    const ushort* Aptr = Ab + (size_t)arow * lda + kg * 8;
    const int nt = K >> 5;

    f32x4 acc[8];
    #pragma unroll
    for (int j = 0; j < 8; ++j) acc[j] = (f32x4)0.f;

    for (int t = 0; t < nt; ++t) {
        short8 a = *(const short8*)(Aptr + t * 32);
        const ushort* Wp = Wb + ((size_t)t * 64 + lane) * 8;
        #pragma unroll
        for (int j = 0; j < 8; ++j) {
            short8 b = *(const short8*)(Wp + (size_t)j * nt * 512);
            acc[j] = __builtin_amdgcn_mfma_f32_16x16x32_bf16(a, b, acc[j], 0, 0, 0);
        }
    }
    #pragma unroll
    for (int r = 0; r < 4; ++r) {
        int orow = row0 + kg * 4 + r;
        if (orow >= nrows) continue;
        #pragma unroll
        for (int j = 0; j < 8; ++j) {
            float v = acc[j][r];
            int col = j * 16 + c;
            if (BIAS) v += bias[col];
            if (RELU) v = fmaxf(v, 0.f);
            outb[(size_t)orow * 128 + col] = (ushort)bfbits(v);
        }
    }
}

// ------------------------------------------------------- sparse aggregation
__global__ __launch_bounds__(256) void agg_kernel(
    const uint* __restrict__ xwb, const int* __restrict__ rowptr,
    const uint2* __restrict__ ecv,
    const float* __restrict__ dinv, const float* __restrict__ bias,
    uint* __restrict__ outu, int ldo, int coff, int n)
{
    int node = (int)((blockIdx.x * (size_t)blockDim.x + threadIdx.x) >> 6);
    int lane = threadIdx.x & 63;
    if (node >= n) return;
    float d  = dinv[node];
    float sw = d * d;                      // self-loop weight
    uint  g  = xwb[(size_t)node * 64 + lane];
    float ax = bflo(g) * sw, ay = bfhi(g) * sw;
    int e0 = rowptr[node], e1 = rowptr[node + 1];
    int e = e0;
    for (; e + 2 <= e1; e += 2) {
        uint2 cv0 = ecv[e], cv1 = ecv[e + 1];
        uint g0 = xwb[(size_t)cv0.x * 64 + lane];
        uint g1 = xwb[(size_t)cv1.x * 64 + lane];
        float v0 = __uint_as_float(cv0.y), v1 = __uint_as_float(cv1.y);
        ax = fmaf(v0, bflo(g0), ax);
        ay = fmaf(v0, bfhi(g0), ay);
        ax = fmaf(v1, bflo(g1), ax);
        ay = fmaf(v1, bfhi(g1), ay);
    }
    if (e < e1) {
        uint2 cv = ecv[e];
        uint gg = xwb[(size_t)cv.x * 64 + lane];
        float v = __uint_as_float(cv.y);
        ax = fmaf(v, bflo(gg), ax);
        ay = fmaf(v, bfhi(gg), ay);
    }
    float2 b = *(const float2*)&bias[lane * 2];
    ax = fmaxf(ax + b.x, 0.f);
    ay = fmaxf(ay + b.y, 0.f);
    outu[(size_t)node * ldo + coff + lane] = bfbits(ax) | (bfbits(ay) << 16);
}

// ---------------------------------------------------------------- pooling
static constexpr int NPP = 32;
__global__ __launch_bounds__(128) void pool_kernel(
    const ushort* __restrict__ h, const int* __restrict__ batch,
    float* __restrict__ z, int zoff, int n)
{
    int f  = threadIdx.x;
    int n0 = blockIdx.x * NPP;
    if (n0 >= n) return;
    int nend = n0 + NPP; if (nend > n) nend = n;
    int cur = batch[n0];
    float acc = 0.f;
    for (int node = n0; node < nend; ++node) {
        int b = batch[node];                  // wave-uniform
        if (b != cur) {
            atomicAdd(&z[(size_t)cur * 384 + zoff + f], acc);
            acc = 0.f; cur = b;
        }
        acc += bf2f(h[(size_t)node * 128 + f]);
    }
    atomicAdd(&z[(size_t)cur * 384 + zoff + f], acc);
}

// ---------------------------------------------------------------- head
__global__ __launch_bounds__(128) void head_kernel(
    const float* __restrict__ z,
    const float* __restrict__ g,  const float* __restrict__ be,
    const float* __restrict__ mu, const float* __restrict__ var,
    const float* __restrict__ w1, const float* __restrict__ b1,
    const float* __restrict__ w2, const float* __restrict__ b2,
    float* __restrict__ out)
{
    int gi = blockIdx.x;
    int t  = threadIdx.x;
    __shared__ float zs[384];
    __shared__ float h1[128];
    __shared__ float lg[10];
    for (int i = t; i < 384; i += 128) {
        float v = z[(size_t)gi * 384 + i];
        v = (v - mu[i]) * rsqrtf(var[i] + 1e-5f) * g[i] + be[i];
        zs[i] = v;
    }
    __syncthreads();
    float acc = b1[t];
    for (int k = 0; k < 384; ++k) acc = fmaf(zs[k], w1[(size_t)k * 128 + t], acc);
    h1[t] = fmaxf(acc, 0.f);
    __syncthreads();
    if (t < 10) {
        float a2 = b2[t];
        for (int k = 0; k < 128; ++k) a2 = fmaf(h1[k], w2[(size_t)k * 10 + t], a2);
        lg[t] = a2;
    }
    __syncthreads();
    if (t == 0) {
        float m = lg[0];
        for (int i = 1; i < 10; ++i) m = fmaxf(m, lg[i]);
        float e[10], s = 0.f;
        for (int i = 0; i < 10; ++i) { e[i] = expf(lg[i] - m); s += e[i]; }
        float inv = 1.f / s;
        for (int i = 0; i < 10; ++i) out[(size_t)gi * 10 + i] = e[i] * inv;
    }
}

// ---------------------------------------------------------------- launch
extern "C" void kernel_launch(void* const* d_in, const int* in_sizes, int n_in,
                              void* d_out, int out_size, void* d_ws, size_t ws_size,
                              hipStream_t stream)
{
    const float* x      = (const float*)d_in[0];
    const float* ea     = (const float*)d_in[1];
    const float* conv_w = (const float*)d_in[2];
    const float* conv_b = (const float*)d_in[3];
    const float* jk_w   = (const float*)d_in[4];
    const float* jk_b   = (const float*)d_in[5];
    const float* bn_g   = (const float*)d_in[6];
    const float* bn_b   = (const float*)d_in[7];
    const float* bn_m   = (const float*)d_in[8];
    const float* bn_v   = (const float*)d_in[9];
    const float* w1     = (const float*)d_in[10];
    const float* b1     = (const float*)d_in[11];
    const float* w2     = (const float*)d_in[12];
    const float* b2     = (const float*)d_in[13];
    const int*   eidx   = (const int*)d_in[14];
    const int*   batch  = (const int*)d_in[15];
    const int* srcv = eidx;
    const int* dstv = eidx + NE;
    float* out = (float*)d_out;

    char* ws = (char*)d_ws;
    size_t off = 0;
    auto alloc = [&](size_t b) { size_t o = off; off += (b + 511) & ~(size_t)511; return o; };
    u64*   pk     = (u64*)  (ws + alloc((size_t)NN * 8));
    int*   cursor = (int*)  (ws + alloc((size_t)NN * 4));
    float* z      = (float*)(ws + alloc((size_t)NG * 384 * 4));
    size_t zero_bytes = off;
    float* dinv   = (float*)(ws + alloc((size_t)NN * 4));
    int*   rowptr = (int*)  (ws + alloc((size_t)(NN + 1) * 4));
    uint2* ecv    = (uint2*)(ws + alloc((size_t)NE * 8));
    ushort* xb    = (ushort*)(ws + alloc((size_t)NN * 128 * 2));
    ushort* wbc   = (ushort*)(ws + alloc((size_t)6 * 128 * 128 * 2));
    ushort* wbj   = (ushort*)(ws + alloc((size_t)3 * 256 * 128 * 2));
    uint*  xwb    = (uint*) (ws + alloc((size_t)NN * 64 * 4));
    uint*  xsb    = (uint*) (ws + alloc((size_t)NN * 128 * 4));   // [NN][256] bf16
    ushort* houtb = (ushort*)(ws + alloc((size_t)NN * 128 * 2));
    int*   bsum   = (int*)  (ws + alloc((size_t)256 * 4));
    int*   boff   = (int*)  (ws + alloc((size_t)257 * 4));
    (void)ws_size; (void)in_sizes; (void)n_in; (void)out_size;

    hipMemsetAsync(d_ws, 0, zero_bytes, stream);

    const int EB  = (NE + 255) / 256;
    const int NB  = (NN + 255) / 256;
    hist_kernel<<<EB, 256, 0, stream>>>(dstv, ea, pk, NE);
    dinv_kernel<<<NB, 256, 0, stream>>>(pk, dinv, NN);
    scan_bsum_kernel<<<NB, 256, 0, stream>>>(pk, bsum, NN);
    scan_boff_kernel<<<1, 256, 0, stream>>>(bsum, boff, NB);
    scan_final_kernel<<<NB, 256, 0, stream>>>(pk, boff, rowptr, NN, NB);
    fill_kernel<<<EB, 256, 0, stream>>>(srcv, dstv, ea, dinv, rowptr, cursor,
                                        ecv, NE);
    cvtx_kernel<<<(NN * 32 + 255) / 256, 256, 0, stream>>>(x, xb, NN * 128);
    wfrag_kernel<<<dim3(64, 6),  256, 0, stream>>>(conv_w, wbc, 128, 128 * 128, 128 * 128);
    wfrag_kernel<<<dim3(128, 3), 256, 0, stream>>>(jk_w,   wbj, 256, 256 * 128, 256 * 128);

    const int GB = (NN + 63) / 64;
    const int AB = (NN * 64 + 255) / 256;
    const int PB = (NN + NPP - 1) / NPP;

    const ushort* hin = xb;
    int lda = 128;
    for (int l = 0; l < 3; ++l) {
        for (int k = 0; k < 2; ++k) {
            gemm_mfma_kernel<false, false><<<GB, 256, 0, stream>>>(
                hin, 128, lda, wbc + (size_t)(l * 2 + k) * 128 * 128, nullptr,
                (ushort*)xwb, NN);
            agg_kernel<<<AB, 256, 0, stream>>>(
                xwb, rowptr, ecv, dinv, conv_b + (size_t)(l * 2 + k) * 128,
                xsb, 128, k * 64, NN);
            hin = (const ushort*)xsb;   // x1 lives in cols 0..127 of xsb
            lda = 256;
        }
        gemm_mfma_kernel<true, true><<<GB, 256, 0, stream>>>(
            (const ushort*)xsb, 256, 256, wbj + (size_t)l * 256 * 128,
            jk_b + (size_t)l * 128, houtb, NN);
        pool_kernel<<<PB, 128, 0, stream>>>(houtb, batch, z, l * 128, NN);
        hin = houtb;
        lda = 128;
    }
    head_kernel<<<NG, 128, 0, stream>>>(z, bn_g, bn_b, bn_m, bn_v,
                                        w1, b1, w2, b2, out);
}

// Round 5
// 618.596 us; speedup vs baseline: 2.3133x; 1.1725x over previous
//
#include <hip/hip_runtime.h>

static constexpr int NN = 50000;   // nodes
static constexpr int NE = 800000;  // edges
static constexpr int NG = 512;     // graphs

typedef unsigned int uint;
typedef unsigned short ushort;
typedef unsigned long long u64;
typedef __attribute__((ext_vector_type(8))) short short8;
typedef __attribute__((ext_vector_type(4))) float f32x4;

__device__ inline uint bfbits(float f) {
    uint u = __float_as_uint(f);
    return (u + 0x7fffu + ((u >> 16) & 1u)) >> 16;   // RNE to bf16
}
__device__ inline float bflo(uint g) { return __uint_as_float(g << 16); }
__device__ inline float bfhi(uint g) { return __uint_as_float(g & 0xffff0000u); }
__device__ inline float bf2f(ushort s) { return __uint_as_float(((uint)s) << 16); }

// ---------------------------------------------------------------- histogram
// one u64 atomic: count in [40,64), fixed-point (2^-24) ew-sum in [0,40)
__global__ void hist_kernel(const int* __restrict__ dst, const float* __restrict__ ew,
                            u64* __restrict__ pk, int nE)
{
    int i = blockIdx.x * blockDim.x + threadIdx.x;
    if (i < nE) {
        int d = dst[i];
        u64 v = (1ULL << 40) + (u64)(ew[i] * 16777216.0f + 0.5f);
        atomicAdd(&pk[d], v);
    }
}

// ------------------------------- scan level 1 (+ fused dinv computation)
__global__ __launch_bounds__(256) void scan_bsum_kernel(const u64* __restrict__ pk,
                                                        int* __restrict__ bsum,
                                                        float* __restrict__ dinv, int n)
{
    __shared__ int wred[4];
    int i = blockIdx.x * 256 + threadIdx.x;
    int v = 0;
    if (i < n) {
        u64 p = pk[i];
        v = (int)(p >> 40);
        float deg = (float)(p & 0xFFFFFFFFFFULL) * (1.0f / 16777216.0f) + 1.0f;
        dinv[i] = rsqrtf(deg);
    }
    int s = v;
    #pragma unroll
    for (int o = 32; o > 0; o >>= 1) s += __shfl_down(s, o, 64);
    int wid = threadIdx.x >> 6;
    if ((threadIdx.x & 63) == 0) wred[wid] = s;
    __syncthreads();
    if (threadIdx.x == 0)
        bsum[blockIdx.x] = wred[0] + wred[1] + wred[2] + wred[3];
}

__global__ __launch_bounds__(256) void scan_boff_kernel(const int* __restrict__ bsum,
                                                        int* __restrict__ boff, int nbs)
{
    __shared__ int sh[256];
    int tid = threadIdx.x;
    int v = (tid < nbs) ? bsum[tid] : 0;
    sh[tid] = v;
    __syncthreads();
    #pragma unroll
    for (int o = 1; o < 256; o <<= 1) {
        int t = (tid >= o) ? sh[tid - o] : 0;
        __syncthreads();
        sh[tid] += t;
        __syncthreads();
    }
    if (tid < nbs) boff[tid] = sh[tid] - v;        // exclusive
    if (tid == 255) boff[nbs] = sh[255];           // total
}

__global__ __launch_bounds__(256) void scan_final_kernel(const u64* __restrict__ pk,
                                                         const int* __restrict__ boff,
                                                         int* __restrict__ rowptr,
                                                         int n, int nbs)
{
    __shared__ int sh[256];
    int tid = threadIdx.x;
    int i = blockIdx.x * 256 + tid;
    int v = (i < n) ? (int)(pk[i] >> 40) : 0;
    sh[tid] = v;
    __syncthreads();
    #pragma unroll
    for (int o = 1; o < 256; o <<= 1) {
        int t = (tid >= o) ? sh[tid - o] : 0;
        __syncthreads();
        sh[tid] += t;
        __syncthreads();
    }
    if (i < n) rowptr[i] = boff[blockIdx.x] + sh[tid] - v;
    if (blockIdx.x == 0 && tid == 0) rowptr[n] = boff[nbs];
}

// edge record: col = src, val = ew * dinv[src]   (dinv[dst] factored into agg)
__global__ void fill_kernel(const int* __restrict__ src, const int* __restrict__ dst,
                            const float* __restrict__ ew, const float* __restrict__ dinv,
                            const int* __restrict__ rowptr, int* __restrict__ cursor,
                            uint2* __restrict__ ecv, int nE)
{
    int i = blockIdx.x * blockDim.x + threadIdx.x;
    if (i < nE) {
        int s = src[i], d = dst[i];
        int pos = rowptr[d] + atomicAdd(&cursor[d], 1);
        uint2 cv;
        cv.x = (uint)s;
        cv.y = __float_as_uint(ew[i] * dinv[s]);
        ecv[pos] = cv;
    }
}

// ---------------------------------------------------------------- x -> bf16
__global__ void cvtx_kernel(const float* __restrict__ x, ushort* __restrict__ xb, int n)
{
    int i = (blockIdx.x * blockDim.x + threadIdx.x) * 4;
    if (i < n) {
        float4 v = *(const float4*)&x[i];
        uint2 p;
        p.x = bfbits(v.x) | (bfbits(v.y) << 16);
        p.y = bfbits(v.z) | (bfbits(v.w) << 16);
        *(uint2*)&xb[i] = p;
    }
}

// ------------------------------------------- W -> bf16 fragment layout
// dst idx = ((j*nt + t)*64 + lane)*8 + e  <-  src[k*128 + col]
// k = t*32 + (lane>>4)*8 + e, col = j*16 + (lane&15), nt = K/32
__global__ void wfrag_kernel(const float* __restrict__ src, ushort* __restrict__ dst,
                             int K, int wstride_src, int wstride_dst)
{
    int wid = blockIdx.y;
    const float* s = src + (size_t)wid * wstride_src;
    ushort* d = dst + (size_t)wid * wstride_dst;
    int i = blockIdx.x * 256 + threadIdx.x;          // < K*128
    int e = i & 7;
    int lane = (i >> 3) & 63;
    int rest = i >> 9;
    int nt = K >> 5;
    int t = rest % nt;
    int j = rest / nt;
    int k = t * 32 + (lane >> 4) * 8 + e;
    int col = j * 16 + (lane & 15);
    d[i] = (ushort)bfbits(s[(size_t)k * 128 + col]);
}

// ---------------------------------------------------------------- MFMA GEMM
// outb[nrows x 128] (bf16) = Ab[nrows x lda][0:K] (bf16) @ W-frag, fp32 acc
template<bool RELU, bool BIAS>
__global__ __launch_bounds__(256) void gemm_mfma_kernel(
    const ushort* __restrict__ Ab, int K, int lda,
    const ushort* __restrict__ Wb, const float* __restrict__ bias,
    ushort* __restrict__ outb, int nrows)
{
    const int wid  = threadIdx.x >> 6;
    const int lane = threadIdx.x & 63;
    const int row0 = blockIdx.x * 64 + wid * 16;
    const int c    = lane & 15;
    const int kg   = lane >> 4;
    int arow = row0 + c;
    if (arow >= nrows) arow = nrows - 1;             // clamp; stores guarded
    const ushort* Aptr = Ab + (size_t)arow * lda + kg * 8;
    const int nt = K >> 5;

    f32x4 acc[8];
    #pragma unroll
    for (int j = 0; j < 8; ++j) acc[j] = (f32x4)0.f;

    for (int t = 0; t < nt; ++t) {
        short8 a = *(const short8*)(Aptr + t * 32);
        const ushort* Wp = Wb + ((size_t)t * 64 + lane) * 8;
        #pragma unroll
        for (int j = 0; j < 8; ++j) {
            short8 b = *(const short8*)(Wp + (size_t)j * nt * 512);
            acc[j] = __builtin_amdgcn_mfma_f32_16x16x32_bf16(a, b, acc[j], 0, 0, 0);
        }
    }
    #pragma unroll
    for (int r = 0; r < 4; ++r) {
        int orow = row0 + kg * 4 + r;
        if (orow >= nrows) continue;
        #pragma unroll
        for (int j = 0; j < 8; ++j) {
            float v = acc[j][r];
            int col = j * 16 + c;
            if (BIAS) v += bias[col];
            if (RELU) v = fmaxf(v, 0.f);
            outb[(size_t)orow * 128 + col] = (ushort)bfbits(v);
        }
    }
}

// ------------------------------------------------------- sparse aggregation
// one wave per node; lane holds 2 feats. Deep-unrolled for MLP (latency-bound).
__global__ __launch_bounds__(256) void agg_kernel(
    const uint* __restrict__ xwb, const int* __restrict__ rowptr,
    const uint2* __restrict__ ecv,
    const float* __restrict__ dinv, const float* __restrict__ bias,
    uint* __restrict__ outu, int ldo, int coff, int n)
{
    int node = (int)((blockIdx.x * (size_t)blockDim.x + threadIdx.x) >> 6);
    int lane = threadIdx.x & 63;
    if (node >= n) return;
    float d = dinv[node];
    uint  g = xwb[(size_t)node * 64 + lane];
    float bx = 0.f, by = 0.f;              // edge sum (excludes dinv[dst])
    int e0 = rowptr[node], e1 = rowptr[node + 1];
    int e = e0;
    for (; e + 8 <= e1; e += 8) {          // 8 gathers in flight
        uint2 cv[8];
        #pragma unroll
        for (int q = 0; q < 8; ++q) cv[q] = ecv[e + q];
        uint gq[8];
        #pragma unroll
        for (int q = 0; q < 8; ++q) gq[q] = xwb[(size_t)cv[q].x * 64 + lane];
        #pragma unroll
        for (int q = 0; q < 8; ++q) {
            float v = __uint_as_float(cv[q].y);
            bx = fmaf(v, bflo(gq[q]), bx);
            by = fmaf(v, bfhi(gq[q]), by);
        }
    }
    for (; e + 4 <= e1; e += 4) {
        uint2 cv[4];
        #pragma unroll
        for (int q = 0; q < 4; ++q) cv[q] = ecv[e + q];
        uint gq[4];
        #pragma unroll
        for (int q = 0; q < 4; ++q) gq[q] = xwb[(size_t)cv[q].x * 64 + lane];
        #pragma unroll
        for (int q = 0; q < 4; ++q) {
            float v = __uint_as_float(cv[q].y);
            bx = fmaf(v, bflo(gq[q]), bx);
            by = fmaf(v, bfhi(gq[q]), by);
        }
    }
    for (; e < e1; ++e) {
        uint2 cv = ecv[e];
        uint gg = xwb[(size_t)cv.x * 64 + lane];
        float v = __uint_as_float(cv.y);
        bx = fmaf(v, bflo(gg), bx);
        by = fmaf(v, bfhi(gg), by);
    }
    float sw = d * d;                       // self-loop weight
    float ax = fmaf(d, bx, bflo(g) * sw);
    float ay = fmaf(d, by, bfhi(g) * sw);
    float2 b = *(const float2*)&bias[lane * 2];
    ax = fmaxf(ax + b.x, 0.f);
    ay = fmaxf(ay + b.y, 0.f);
    outu[(size_t)node * ldo + coff + lane] = bfbits(ax) | (bfbits(ay) << 16);
}

// ---------------------------------------------------------------- pooling
static constexpr int NPP = 32;
__global__ __launch_bounds__(128) void pool_kernel(
    const ushort* __restrict__ h, const int* __restrict__ batch,
    float* __restrict__ z, int zoff, int n)
{
    int f  = threadIdx.x;
    int n0 = blockIdx.x * NPP;
    if (n0 >= n) return;
    int nend = n0 + NPP; if (nend > n) nend = n;
    int cur = batch[n0];
    float acc = 0.f;
    for (int node = n0; node < nend; ++node) {
        int b = batch[node];                  // wave-uniform
        if (b != cur) {
            atomicAdd(&z[(size_t)cur * 384 + zoff + f], acc);
            acc = 0.f; cur = b;
        }
        acc += bf2f(h[(size_t)node * 128 + f]);
    }
    atomicAdd(&z[(size_t)cur * 384 + zoff + f], acc);
}

// ---------------------------------------------------------------- head
__global__ __launch_bounds__(128) void head_kernel(
    const float* __restrict__ z,
    const float* __restrict__ g,  const float* __restrict__ be,
    const float* __restrict__ mu, const float* __restrict__ var,
    const float* __restrict__ w1, const float* __restrict__ b1,
    const float* __restrict__ w2, const float* __restrict__ b2,
    float* __restrict__ out)
{
    int gi = blockIdx.x;
    int t  = threadIdx.x;
    __shared__ float zs[384];
    __shared__ float h1[128];
    __shared__ float lg[10];
    for (int i = t; i < 384; i += 128) {
        float v = z[(size_t)gi * 384 + i];
        v = (v - mu[i]) * rsqrtf(var[i] + 1e-5f) * g[i] + be[i];
        zs[i] = v;
    }
    __syncthreads();
    float acc = b1[t];
    for (int k = 0; k < 384; ++k) acc = fmaf(zs[k], w1[(size_t)k * 128 + t], acc);
    h1[t] = fmaxf(acc, 0.f);
    __syncthreads();
    if (t < 10) {
        float a2 = b2[t];
        for (int k = 0; k < 128; ++k) a2 = fmaf(h1[k], w2[(size_t)k * 10 + t], a2);
        lg[t] = a2;
    }
    __syncthreads();
    if (t == 0) {
        float m = lg[0];
        for (int i = 1; i < 10; ++i) m = fmaxf(m, lg[i]);
        float e[10], s = 0.f;
        for (int i = 0; i < 10; ++i) { e[i] = expf(lg[i] - m); s += e[i]; }
        float inv = 1.f / s;
        for (int i = 0; i < 10; ++i) out[(size_t)gi * 10 + i] = e[i] * inv;
    }
}

// ---------------------------------------------------------------- launch
extern "C" void kernel_launch(void* const* d_in, const int* in_sizes, int n_in,
                              void* d_out, int out_size, void* d_ws, size_t ws_size,
                              hipStream_t stream)
{
    const float* x      = (const float*)d_in[0];
    const float* ea     = (const float*)d_in[1];
    const float* conv_w = (const float*)d_in[2];
    const float* conv_b = (const float*)d_in[3];
    const float* jk_w   = (const float*)d_in[4];
    const float* jk_b   = (const float*)d_in[5];
    const float* bn_g   = (const float*)d_in[6];
    const float* bn_b   = (const float*)d_in[7];
    const float* bn_m   = (const float*)d_in[8];
    const float* bn_v   = (const float*)d_in[9];
    const float* w1     = (const float*)d_in[10];
    const float* b1     = (const float*)d_in[11];
    const float* w2     = (const float*)d_in[12];
    const float* b2     = (const float*)d_in[13];
    const int*   eidx   = (const int*)d_in[14];
    const int*   batch  = (const int*)d_in[15];
    const int* srcv = eidx;
    const int* dstv = eidx + NE;
    float* out = (float*)d_out;

    char* ws = (char*)d_ws;
    size_t off = 0;
    auto alloc = [&](size_t b) { size_t o = off; off += (b + 511) & ~(size_t)511; return o; };
    u64*   pk     = (u64*)  (ws + alloc((size_t)NN * 8));
    int*   cursor = (int*)  (ws + alloc((size_t)NN * 4));
    float* z      = (float*)(ws + alloc((size_t)NG * 384 * 4));
    size_t zero_bytes = off;
    float* dinv   = (float*)(ws + alloc((size_t)NN * 4));
    int*   rowptr = (int*)  (ws + alloc((size_t)(NN + 1) * 4));
    uint2* ecv    = (uint2*)(ws + alloc((size_t)NE * 8));
    ushort* xb    = (ushort*)(ws + alloc((size_t)NN * 128 * 2));
    ushort* wbc   = (ushort*)(ws + alloc((size_t)6 * 128 * 128 * 2));
    ushort* wbj   = (ushort*)(ws + alloc((size_t)3 * 256 * 128 * 2));
    uint*  xwb    = (uint*) (ws + alloc((size_t)NN * 64 * 4));
    uint*  xsb    = (uint*) (ws + alloc((size_t)NN * 128 * 4));   // [NN][256] bf16
    ushort* houtb = (ushort*)(ws + alloc((size_t)NN * 128 * 2));
    int*   bsum   = (int*)  (ws + alloc((size_t)256 * 4));
    int*   boff   = (int*)  (ws + alloc((size_t)257 * 4));
    (void)ws_size; (void)in_sizes; (void)n_in; (void)out_size;

    hipMemsetAsync(d_ws, 0, zero_bytes, stream);

    const int EB  = (NE + 255) / 256;
    const int NB  = (NN + 255) / 256;
    hist_kernel<<<EB, 256, 0, stream>>>(dstv, ea, pk, NE);
    scan_bsum_kernel<<<NB, 256, 0, stream>>>(pk, bsum, dinv, NN);
    scan_boff_kernel<<<1, 256, 0, stream>>>(bsum, boff, NB);
    scan_final_kernel<<<NB, 256, 0, stream>>>(pk, boff, rowptr, NN, NB);
    fill_kernel<<<EB, 256, 0, stream>>>(srcv, dstv, ea, dinv, rowptr, cursor,
                                        ecv, NE);
    cvtx_kernel<<<(NN * 32 + 255) / 256, 256, 0, stream>>>(x, xb, NN * 128);
    wfrag_kernel<<<dim3(64, 6),  256, 0, stream>>>(conv_w, wbc, 128, 128 * 128, 128 * 128);
    wfrag_kernel<<<dim3(128, 3), 256, 0, stream>>>(jk_w,   wbj, 256, 256 * 128, 256 * 128);

    const int GB = (NN + 63) / 64;
    const int AB = (NN * 64 + 255) / 256;
    const int PB = (NN + NPP - 1) / NPP;

    const ushort* hin = xb;
    int lda = 128;
    for (int l = 0; l < 3; ++l) {
        for (int k = 0; k < 2; ++k) {
            gemm_mfma_kernel<false, false><<<GB, 256, 0, stream>>>(
                hin, 128, lda, wbc + (size_t)(l * 2 + k) * 128 * 128, nullptr,
                (ushort*)xwb, NN);
            agg_kernel<<<AB, 256, 0, stream>>>(
                xwb, rowptr, ecv, dinv, conv_b + (size_t)(l * 2 + k) * 128,
                xsb, 128, k * 64, NN);
            hin = (const ushort*)xsb;   // x1 lives in cols 0..127 of xsb
            lda = 256;
        }
        gemm_mfma_kernel<true, true><<<GB, 256, 0, stream>>>(
            (const ushort*)xsb, 256, 256, wbj + (size_t)l * 256 * 128,
            jk_b + (size_t)l * 128, houtb, NN);
        pool_kernel<<<PB, 128, 0, stream>>>(houtb, batch, z, l * 128, NN);
        hin = houtb;
        lda = 128;
    }
    head_kernel<<<NG, 128, 0, stream>>>(z, bn_g, bn_b, bn_m, bn_v,
                                        w1, b1, w2, b2, out);
}

// Round 6
// 588.567 us; speedup vs baseline: 2.4313x; 1.0510x over previous
//
#include <hip/hip_runtime.h>
#include <hip/hip_fp16.h>

static constexpr int NN = 50000;   // nodes
static constexpr int NE = 800000;  // edges
static constexpr int NG = 512;     // graphs

typedef unsigned int uint;
typedef unsigned short ushort;
typedef unsigned long long u64;
typedef __attribute__((ext_vector_type(8))) short short8;
typedef __attribute__((ext_vector_type(4))) float f32x4;

__device__ inline uint bfbits(float f) {
    uint u = __float_as_uint(f);
    return (u + 0x7fffu + ((u >> 16) & 1u)) >> 16;   // RNE to bf16
}
__device__ inline float bflo(uint g) { return __uint_as_float(g << 16); }
__device__ inline float bfhi(uint g) { return __uint_as_float(g & 0xffff0000u); }
__device__ inline float bf2f(ushort s) { return __uint_as_float(((uint)s) << 16); }

// ---------------------------------------------------------------- histogram
// one u64 atomic: count in [40,64), fixed-point (2^-24) ew-sum in [0,40).
// atomic return value's count field = this edge's rank within its dst bucket.
__global__ void hist_kernel(const int* __restrict__ dst, const float* __restrict__ ew,
                            u64* __restrict__ pk, ushort* __restrict__ rankb, int nE)
{
    int i = blockIdx.x * blockDim.x + threadIdx.x;
    if (i < nE) {
        int d = dst[i];
        u64 v = (1ULL << 40) + (u64)(ew[i] * 16777216.0f + 0.5f);
        u64 old = atomicAdd(&pk[d], v);
        rankb[i] = (ushort)(old >> 40);
    }
}

// ------------------------------- scan level 1 (+ fused dinv computation)
__global__ __launch_bounds__(256) void scan_bsum_kernel(const u64* __restrict__ pk,
                                                        int* __restrict__ bsum,
                                                        float* __restrict__ dinv, int n)
{
    __shared__ int wred[4];
    int i = blockIdx.x * 256 + threadIdx.x;
    int v = 0;
    if (i < n) {
        u64 p = pk[i];
        v = (int)(p >> 40);
        float deg = (float)(p & 0xFFFFFFFFFFULL) * (1.0f / 16777216.0f) + 1.0f;
        dinv[i] = rsqrtf(deg);
    }
    int s = v;
    #pragma unroll
    for (int o = 32; o > 0; o >>= 1) s += __shfl_down(s, o, 64);
    int wid = threadIdx.x >> 6;
    if ((threadIdx.x & 63) == 0) wred[wid] = s;
    __syncthreads();
    if (threadIdx.x == 0)
        bsum[blockIdx.x] = wred[0] + wred[1] + wred[2] + wred[3];
}

__global__ __launch_bounds__(256) void scan_boff_kernel(const int* __restrict__ bsum,
                                                        int* __restrict__ boff, int nbs)
{
    __shared__ int sh[256];
    int tid = threadIdx.x;
    int v = (tid < nbs) ? bsum[tid] : 0;
    sh[tid] = v;
    __syncthreads();
    #pragma unroll
    for (int o = 1; o < 256; o <<= 1) {
        int t = (tid >= o) ? sh[tid - o] : 0;
        __syncthreads();
        sh[tid] += t;
        __syncthreads();
    }
    if (tid < nbs) boff[tid] = sh[tid] - v;        // exclusive
    if (tid == 255) boff[nbs] = sh[255];           // total
}

__global__ __launch_bounds__(256) void scan_final_kernel(const u64* __restrict__ pk,
                                                         const int* __restrict__ boff,
                                                         int* __restrict__ rowptr,
                                                         int n, int nbs)
{
    __shared__ int sh[256];
    int tid = threadIdx.x;
    int i = blockIdx.x * 256 + tid;
    int v = (i < n) ? (int)(pk[i] >> 40) : 0;
    sh[tid] = v;
    __syncthreads();
    #pragma unroll
    for (int o = 1; o < 256; o <<= 1) {
        int t = (tid >= o) ? sh[tid - o] : 0;
        __syncthreads();
        sh[tid] += t;
        __syncthreads();
    }
    if (i < n) rowptr[i] = boff[blockIdx.x] + sh[tid] - v;
    if (blockIdx.x == 0 && tid == 0) rowptr[n] = boff[nbs];
}

// edge record (4B): low16 = src id, high16 = fp16(ew * dinv[src])
// (dinv[dst] factored into agg epilogue). No atomics: rank precomputed in hist.
__global__ void fill_kernel(const int* __restrict__ src, const int* __restrict__ dst,
                            const float* __restrict__ ew, const float* __restrict__ dinv,
                            const int* __restrict__ rowptr,
                            const ushort* __restrict__ rankb,
                            uint* __restrict__ ecv, int nE)
{
    int i = blockIdx.x * blockDim.x + threadIdx.x;
    if (i < nE) {
        int s = src[i], d = dst[i];
        int pos = rowptr[d] + (int)rankb[i];
        float v = ew[i] * dinv[s];
        ecv[pos] = (uint)s | ((uint)__half_as_ushort(__float2half_rn(v)) << 16);
    }
}

// ---------------------------------------------------------------- x -> bf16
__global__ void cvtx_kernel(const float* __restrict__ x, ushort* __restrict__ xb, int n)
{
    int i = (blockIdx.x * blockDim.x + threadIdx.x) * 4;
    if (i < n) {
        float4 v = *(const float4*)&x[i];
        uint2 p;
        p.x = bfbits(v.x) | (bfbits(v.y) << 16);
        p.y = bfbits(v.z) | (bfbits(v.w) << 16);
        *(uint2*)&xb[i] = p;
    }
}

// ------------------------------------------- W -> bf16 fragment layout
// dst idx = ((j*nt + t)*64 + lane)*8 + e  <-  src[k*128 + col]
// k = t*32 + (lane>>4)*8 + e, col = j*16 + (lane&15), nt = K/32
__global__ void wfrag_kernel(const float* __restrict__ src, ushort* __restrict__ dst,
                             int K, int wstride_src, int wstride_dst)
{
    int wid = blockIdx.y;
    const float* s = src + (size_t)wid * wstride_src;
    ushort* d = dst + (size_t)wid * wstride_dst;
    int i = blockIdx.x * 256 + threadIdx.x;          // < K*128
    int e = i & 7;
    int lane = (i >> 3) & 63;
    int rest = i >> 9;
    int nt = K >> 5;
    int t = rest % nt;
    int j = rest / nt;
    int k = t * 32 + (lane >> 4) * 8 + e;
    int col = j * 16 + (lane & 15);
    d[i] = (ushort)bfbits(s[(size_t)k * 128 + col]);
}

// ---------------------------------------------------------------- MFMA GEMM
// outb[nrows x 128] (bf16) = Ab[nrows x lda][0:K] (bf16) @ W-frag, fp32 acc
template<bool RELU, bool BIAS>
__global__ __launch_bounds__(256) void gemm_mfma_kernel(
    const ushort* __restrict__ Ab, int K, int lda,
    const ushort* __restrict__ Wb, const float* __restrict__ bias,
    ushort* __restrict__ outb, int nrows)
{
    const int wid  = threadIdx.x >> 6;
    const int lane = threadIdx.x & 63;
    const int row0 = blockIdx.x * 64 + wid * 16;
    const int c    = lane & 15;
    const int kg   = lane >> 4;
    int arow = row0 + c;
    if (arow >= nrows) arow = nrows - 1;             // clamp; stores guarded
    const ushort* Aptr = Ab + (size_t)arow * lda + kg * 8;
    const int nt = K >> 5;

    f32x4 acc[8];
    #pragma unroll
    for (int j = 0; j < 8; ++j) acc[j] = (f32x4)0.f;

    for (int t = 0; t < nt; ++t) {
        short8 a = *(const short8*)(Aptr + t * 32);
        const ushort* Wp = Wb + ((size_t)t * 64 + lane) * 8;
        #pragma unroll
        for (int j = 0; j < 8; ++j) {
            short8 b = *(const short8*)(Wp + (size_t)j * nt * 512);
            acc[j] = __builtin_amdgcn_mfma_f32_16x16x32_bf16(a, b, acc[j], 0, 0, 0);
        }
    }
    #pragma unroll
    for (int r = 0; r < 4; ++r) {
        int orow = row0 + kg * 4 + r;
        if (orow >= nrows) continue;
        #pragma unroll
        for (int j = 0; j < 8; ++j) {
            float v = acc[j][r];
            int col = j * 16 + c;
            if (BIAS) v += bias[col];
            if (RELU) v = fmaxf(v, 0.f);
            outb[(size_t)orow * 128 + col] = (ushort)bfbits(v);
        }
    }
}

// ------------------------------------------------------- sparse aggregation
// one wave per node; lane holds 2 feats. Deep-unrolled for MLP (latency-bound).
__global__ __launch_bounds__(256) void agg_kernel(
    const uint* __restrict__ xwb, const int* __restrict__ rowptr,
    const uint* __restrict__ ecv,
    const float* __restrict__ dinv, const float* __restrict__ bias,
    uint* __restrict__ outu, int ldo, int coff, int n)
{
    int node = (int)((blockIdx.x * (size_t)blockDim.x + threadIdx.x) >> 6);
    int lane = threadIdx.x & 63;
    if (node >= n) return;
    float d = dinv[node];
    uint  g = xwb[(size_t)node * 64 + lane];
    float bx = 0.f, by = 0.f;              // edge sum (excludes dinv[dst])
    int e0 = rowptr[node], e1 = rowptr[node + 1];
    int e = e0;
    for (; e + 8 <= e1; e += 8) {          // 8 gathers in flight
        uint rec[8];
        #pragma unroll
        for (int q = 0; q < 8; ++q) rec[q] = ecv[e + q];
        uint gq[8];
        #pragma unroll
        for (int q = 0; q < 8; ++q)
            gq[q] = xwb[(size_t)(rec[q] & 0xffffu) * 64 + lane];
        #pragma unroll
        for (int q = 0; q < 8; ++q) {
            float v = __half2float(__ushort_as_half((ushort)(rec[q] >> 16)));
            bx = fmaf(v, bflo(gq[q]), bx);
            by = fmaf(v, bfhi(gq[q]), by);
        }
    }
    for (; e + 4 <= e1; e += 4) {
        uint rec[4];
        #pragma unroll
        for (int q = 0; q < 4; ++q) rec[q] = ecv[e + q];
        uint gq[4];
        #pragma unroll
        for (int q = 0; q < 4; ++q)
            gq[q] = xwb[(size_t)(rec[q] & 0xffffu) * 64 + lane];
        #pragma unroll
        for (int q = 0; q < 4; ++q) {
            float v = __half2float(__ushort_as_half((ushort)(rec[q] >> 16)));
            bx = fmaf(v, bflo(gq[q]), bx);
            by = fmaf(v, bfhi(gq[q]), by);
        }
    }
    for (; e < e1; ++e) {
        uint rec = ecv[e];
        uint gg = xwb[(size_t)(rec & 0xffffu) * 64 + lane];
        float v = __half2float(__ushort_as_half((ushort)(rec >> 16)));
        bx = fmaf(v, bflo(gg), bx);
        by = fmaf(v, bfhi(gg), by);
    }
    float sw = d * d;                       // self-loop weight
    float ax = fmaf(d, bx, bflo(g) * sw);
    float ay = fmaf(d, by, bfhi(g) * sw);
    float2 b = *(const float2*)&bias[lane * 2];
    ax = fmaxf(ax + b.x, 0.f);
    ay = fmaxf(ay + b.y, 0.f);
    outu[(size_t)node * ldo + coff + lane] = bfbits(ax) | (bfbits(ay) << 16);
}

// ---------------------------------------------------------------- pooling
static constexpr int NPP = 32;
__global__ __launch_bounds__(128) void pool_kernel(
    const ushort* __restrict__ h, const int* __restrict__ batch,
    float* __restrict__ z, int zoff, int n)
{
    int f  = threadIdx.x;
    int n0 = blockIdx.x * NPP;
    if (n0 >= n) return;
    int nend = n0 + NPP; if (nend > n) nend = n;
    int cur = batch[n0];
    float acc = 0.f;
    for (int node = n0; node < nend; ++node) {
        int b = batch[node];                  // wave-uniform
        if (b != cur) {
            atomicAdd(&z[(size_t)cur * 384 + zoff + f], acc);
            acc = 0.f; cur = b;
        }
        acc += bf2f(h[(size_t)node * 128 + f]);
    }
    atomicAdd(&z[(size_t)cur * 384 + zoff + f], acc);
}

// ---------------------------------------------------------------- head
__global__ __launch_bounds__(128) void head_kernel(
    const float* __restrict__ z,
    const float* __restrict__ g,  const float* __restrict__ be,
    const float* __restrict__ mu, const float* __restrict__ var,
    const float* __restrict__ w1, const float* __restrict__ b1,
    const float* __restrict__ w2, const float* __restrict__ b2,
    float* __restrict__ out)
{
    int gi = blockIdx.x;
    int t  = threadIdx.x;
    __shared__ float zs[384];
    __shared__ float h1[128];
    __shared__ float lg[10];
    for (int i = t; i < 384; i += 128) {
        float v = z[(size_t)gi * 384 + i];
        v = (v - mu[i]) * rsqrtf(var[i] + 1e-5f) * g[i] + be[i];
        zs[i] = v;
    }
    __syncthreads();
    float acc = b1[t];
    for (int k = 0; k < 384; ++k) acc = fmaf(zs[k], w1[(size_t)k * 128 + t], acc);
    h1[t] = fmaxf(acc, 0.f);
    __syncthreads();
    if (t < 10) {
        float a2 = b2[t];
        for (int k = 0; k < 128; ++k) a2 = fmaf(h1[k], w2[(size_t)k * 10 + t], a2);
        lg[t] = a2;
    }
    __syncthreads();
    if (t == 0) {
        float m = lg[0];
        for (int i = 1; i < 10; ++i) m = fmaxf(m, lg[i]);
        float e[10], s = 0.f;
        for (int i = 0; i < 10; ++i) { e[i] = expf(lg[i] - m); s += e[i]; }
        float inv = 1.f / s;
        for (int i = 0; i < 10; ++i) out[(size_t)gi * 10 + i] = e[i] * inv;
    }
}

// ---------------------------------------------------------------- launch
extern "C" void kernel_launch(void* const* d_in, const int* in_sizes, int n_in,
                              void* d_out, int out_size, void* d_ws, size_t ws_size,
                              hipStream_t stream)
{
    const float* x      = (const float*)d_in[0];
    const float* ea     = (const float*)d_in[1];
    const float* conv_w = (const float*)d_in[2];
    const float* conv_b = (const float*)d_in[3];
    const float* jk_w   = (const float*)d_in[4];
    const float* jk_b   = (const float*)d_in[5];
    const float* bn_g   = (const float*)d_in[6];
    const float* bn_b   = (const float*)d_in[7];
    const float* bn_m   = (const float*)d_in[8];
    const float* bn_v   = (const float*)d_in[9];
    const float* w1     = (const float*)d_in[10];
    const float* b1     = (const float*)d_in[11];
    const float* w2     = (const float*)d_in[12];
    const float* b2     = (const float*)d_in[13];
    const int*   eidx   = (const int*)d_in[14];
    const int*   batch  = (const int*)d_in[15];
    const int* srcv = eidx;
    const int* dstv = eidx + NE;
    float* out = (float*)d_out;

    char* ws = (char*)d_ws;
    size_t off = 0;
    auto alloc = [&](size_t b) { size_t o = off; off += (b + 511) & ~(size_t)511; return o; };
    u64*   pk     = (u64*)  (ws + alloc((size_t)NN * 8));
    float* z      = (float*)(ws + alloc((size_t)NG * 384 * 4));
    size_t zero_bytes = off;
    float* dinv   = (float*)(ws + alloc((size_t)NN * 4));
    int*   rowptr = (int*)  (ws + alloc((size_t)(NN + 1) * 4));
    ushort* rankb = (ushort*)(ws + alloc((size_t)NE * 2));
    uint*  ecv    = (uint*) (ws + alloc((size_t)NE * 4));
    ushort* xb    = (ushort*)(ws + alloc((size_t)NN * 128 * 2));
    ushort* wbc   = (ushort*)(ws + alloc((size_t)6 * 128 * 128 * 2));
    ushort* wbj   = (ushort*)(ws + alloc((size_t)3 * 256 * 128 * 2));
    uint*  xwb    = (uint*) (ws + alloc((size_t)NN * 64 * 4));
    uint*  xsb    = (uint*) (ws + alloc((size_t)NN * 128 * 4));   // [NN][256] bf16
    ushort* houtb = (ushort*)(ws + alloc((size_t)NN * 128 * 2));
    int*   bsum   = (int*)  (ws + alloc((size_t)256 * 4));
    int*   boff   = (int*)  (ws + alloc((size_t)257 * 4));
    (void)ws_size; (void)in_sizes; (void)n_in; (void)out_size;

    hipMemsetAsync(d_ws, 0, zero_bytes, stream);

    const int EB  = (NE + 255) / 256;
    const int NB  = (NN + 255) / 256;
    hist_kernel<<<EB, 256, 0, stream>>>(dstv, ea, pk, rankb, NE);
    scan_bsum_kernel<<<NB, 256, 0, stream>>>(pk, bsum, dinv, NN);
    scan_boff_kernel<<<1, 256, 0, stream>>>(bsum, boff, NB);
    scan_final_kernel<<<NB, 256, 0, stream>>>(pk, boff, rowptr, NN, NB);
    fill_kernel<<<EB, 256, 0, stream>>>(srcv, dstv, ea, dinv, rowptr, rankb,
                                        ecv, NE);
    cvtx_kernel<<<(NN * 32 + 255) / 256, 256, 0, stream>>>(x, xb, NN * 128);
    wfrag_kernel<<<dim3(64, 6),  256, 0, stream>>>(conv_w, wbc, 128, 128 * 128, 128 * 128);
    wfrag_kernel<<<dim3(128, 3), 256, 0, stream>>>(jk_w,   wbj, 256, 256 * 128, 256 * 128);

    const int GB = (NN + 63) / 64;
    const int AB = (NN * 64 + 255) / 256;
    const int PB = (NN + NPP - 1) / NPP;

    const ushort* hin = xb;
    int lda = 128;
    for (int l = 0; l < 3; ++l) {
        for (int k = 0; k < 2; ++k) {
            gemm_mfma_kernel<false, false><<<GB, 256, 0, stream>>>(
                hin, 128, lda, wbc + (size_t)(l * 2 + k) * 128 * 128, nullptr,
                (ushort*)xwb, NN);
            agg_kernel<<<AB, 256, 0, stream>>>(
                xwb, rowptr, ecv, dinv, conv_b + (size_t)(l * 2 + k) * 128,
                xsb, 128, k * 64, NN);
            hin = (const ushort*)xsb;   // x1 lives in cols 0..127 of xsb
            lda = 256;
        }
        gemm_mfma_kernel<true, true><<<GB, 256, 0, stream>>>(
            (const ushort*)xsb, 256, 256, wbj + (size_t)l * 256 * 128,
            jk_b + (size_t)l * 128, houtb, NN);
        pool_kernel<<<PB, 128, 0, stream>>>(houtb, batch, z, l * 128, NN);
        hin = houtb;
        lda = 128;
    }
    head_kernel<<<NG, 128, 0, stream>>>(z, bn_g, bn_b, bn_m, bn_v,
                                        w1, b1, w2, b2, out);
}

// Round 8
// 514.575 us; speedup vs baseline: 2.7809x; 1.1438x over previous
//
#include <hip/hip_runtime.h>
#include <hip/hip_fp16.h>

static constexpr int NN = 50000;   // nodes
static constexpr int NE = 800000;  // edges
static constexpr int NG = 512;     // graphs

typedef unsigned int uint;
typedef unsigned short ushort;
typedef unsigned long long u64;
typedef __attribute__((ext_vector_type(8))) short short8;
typedef __attribute__((ext_vector_type(4))) float f32x4;

__device__ inline uint bfbits(float f) {
    uint u = __float_as_uint(f);
    return (u + 0x7fffu + ((u >> 16) & 1u)) >> 16;   // RNE to bf16
}
__device__ inline float bflo(uint g) { return __uint_as_float(g << 16); }
__device__ inline float bfhi(uint g) { return __uint_as_float(g & 0xffff0000u); }
__device__ inline float bf2f(ushort s) { return __uint_as_float(((uint)s) << 16); }

static constexpr int EB  = (NE + 255) / 256;       // 3125 hist blocks
static constexpr int WBC = 6 * 64;                 // conv wfrag blocks (K=128)
static constexpr int WBJ = 3 * 128;                // jk wfrag blocks (K=256)

// ------------------------------------------------ prep: hist + wfrag (fused)
// blocks [0,EB): histogram; [EB,EB+WBC): conv-W frags; rest: jk-W frags.
__global__ __launch_bounds__(256) void prep_kernel(
    const int* __restrict__ dst, const float* __restrict__ ew,
    u64* __restrict__ pk, ushort* __restrict__ rankb,
    const float* __restrict__ conv_w, ushort* __restrict__ wbc,
    const float* __restrict__ jk_w, ushort* __restrict__ wbj)
{
    int b = blockIdx.x;
    int tid = threadIdx.x;
    if (b < EB) {
        int i = b * 256 + tid;
        if (i < NE) {
            int d = dst[i];
            u64 v = (1ULL << 40) + (u64)(ew[i] * 16777216.0f + 0.5f);
            u64 old = atomicAdd(&pk[d], v);
            rankb[i] = (ushort)(old >> 40);
        }
        return;
    }
    const float* s; ushort* d; int K, blk;
    if (b < EB + WBC) {
        int bb = b - EB;
        int wid = bb >> 6; blk = bb & 63;
        K = 128;
        s = conv_w + (size_t)wid * 128 * 128;
        d = wbc    + (size_t)wid * 128 * 128;
    } else {
        int bb = b - EB - WBC;
        int wid = bb >> 7; blk = bb & 127;
        K = 256;
        s = jk_w + (size_t)wid * 256 * 128;
        d = wbj  + (size_t)wid * 256 * 128;
    }
    int i = blk * 256 + tid;                      // < K*128
    int e = i & 7;
    int lane = (i >> 3) & 63;
    int rest = i >> 9;
    int nt = K >> 5;
    int t = rest % nt;
    int j = rest / nt;
    int k = t * 32 + (lane >> 4) * 8 + e;
    int col = j * 16 + (lane & 15);
    d[i] = (ushort)bfbits(s[(size_t)k * 128 + col]);
}

// -------------------------- scan level 1+2 fused (last-block pattern) + dinv
__global__ __launch_bounds__(256) void scan_ab_kernel(
    const u64* __restrict__ pk, int* __restrict__ bsum, float* __restrict__ dinv,
    int* __restrict__ boff, uint* __restrict__ ctr, int n, int nbs)
{
    __shared__ int wred[4];
    __shared__ int lastf;
    int tid = threadIdx.x;
    int i = blockIdx.x * 256 + tid;
    int v = 0;
    if (i < n) {
        u64 p = pk[i];
        v = (int)(p >> 40);
        float deg = (float)(p & 0xFFFFFFFFFFULL) * (1.0f / 16777216.0f) + 1.0f;
        dinv[i] = rsqrtf(deg);
    }
    int s = v;
    #pragma unroll
    for (int o = 32; o > 0; o >>= 1) s += __shfl_down(s, o, 64);
    int wid = tid >> 6;
    if ((tid & 63) == 0) wred[wid] = s;
    __syncthreads();
    if (tid == 0) {
        bsum[blockIdx.x] = wred[0] + wred[1] + wred[2] + wred[3];
        __threadfence();
        uint old = atomicAdd(ctr, 1u);
        lastf = (old == (uint)(gridDim.x - 1));
    }
    __syncthreads();
    if (!lastf) return;
    __threadfence();                               // acquire all bsum
    __shared__ int sh[256];
    int bv = (tid < nbs) ? bsum[tid] : 0;
    sh[tid] = bv;
    __syncthreads();
    #pragma unroll
    for (int o = 1; o < 256; o <<= 1) {
        int t2 = (tid >= o) ? sh[tid - o] : 0;
        __syncthreads();
        sh[tid] += t2;
        __syncthreads();
    }
    if (tid < nbs) boff[tid] = sh[tid] - bv;       // exclusive
    if (tid == 255) boff[nbs] = sh[255];           // total
}

__global__ __launch_bounds__(256) void scan_final_kernel(const u64* __restrict__ pk,
                                                         const int* __restrict__ boff,
                                                         int* __restrict__ rowptr,
                                                         int n, int nbs)
{
    __shared__ int sh[256];
    int tid = threadIdx.x;
    int i = blockIdx.x * 256 + tid;
    int v = (i < n) ? (int)(pk[i] >> 40) : 0;
    sh[tid] = v;
    __syncthreads();
    #pragma unroll
    for (int o = 1; o < 256; o <<= 1) {
        int t = (tid >= o) ? sh[tid - o] : 0;
        __syncthreads();
        sh[tid] += t;
        __syncthreads();
    }
    if (i < n) rowptr[i] = boff[blockIdx.x] + sh[tid] - v;
    if (blockIdx.x == 0 && tid == 0) rowptr[n] = boff[nbs];
}

// edge record (4B): low16 = src id, high16 = fp16(ew * dinv[src])
__global__ void fill_kernel(const int* __restrict__ src, const int* __restrict__ dst,
                            const float* __restrict__ ew, const float* __restrict__ dinv,
                            const int* __restrict__ rowptr,
                            const ushort* __restrict__ rankb,
                            uint* __restrict__ ecv, int nE)
{
    int i = blockIdx.x * blockDim.x + threadIdx.x;
    if (i < nE) {
        int s = src[i], d = dst[i];
        int pos = rowptr[d] + (int)rankb[i];
        float v = ew[i] * dinv[s];
        ecv[pos] = (uint)s | ((uint)__half_as_ushort(__float2half_rn(v)) << 16);
    }
}

// ---------------------------------------------------------- conv GEMM (MFMA)
// outb[nrows x 128] (bf16) = A[nrows x lda][0:K] @ W-frag.  AF32: A is fp32.
template<bool AF32>
__global__ __launch_bounds__(256) void conv_gemm_kernel(
    const void* __restrict__ Aab, int K, int lda,
    const ushort* __restrict__ Wb,
    ushort* __restrict__ outb, int nrows)
{
    const int wid  = threadIdx.x >> 6;
    const int lane = threadIdx.x & 63;
    const int row0 = blockIdx.x * 64 + wid * 16;
    const int c    = lane & 15;
    const int kg   = lane >> 4;
    int arow = row0 + c;
    if (arow >= nrows) arow = nrows - 1;
    const int nt = K >> 5;

    f32x4 acc[8];
    #pragma unroll
    for (int j = 0; j < 8; ++j) acc[j] = (f32x4)0.f;

    for (int t = 0; t < nt; ++t) {
        short8 a;
        if (AF32) {
            const float* Ap = (const float*)Aab + (size_t)arow * lda + kg * 8 + t * 32;
            float4 f0 = *(const float4*)Ap;
            float4 f1 = *(const float4*)(Ap + 4);
            a[0] = (short)bfbits(f0.x); a[1] = (short)bfbits(f0.y);
            a[2] = (short)bfbits(f0.z); a[3] = (short)bfbits(f0.w);
            a[4] = (short)bfbits(f1.x); a[5] = (short)bfbits(f1.y);
            a[6] = (short)bfbits(f1.z); a[7] = (short)bfbits(f1.w);
        } else {
            a = *(const short8*)((const ushort*)Aab + (size_t)arow * lda + kg * 8 + t * 32);
        }
        const ushort* Wp = Wb + ((size_t)t * 64 + lane) * 8;
        #pragma unroll
        for (int j = 0; j < 8; ++j) {
            short8 b = *(const short8*)(Wp + (size_t)j * nt * 512);
            acc[j] = __builtin_amdgcn_mfma_f32_16x16x32_bf16(a, b, acc[j], 0, 0, 0);
        }
    }
    #pragma unroll
    for (int r = 0; r < 4; ++r) {
        int orow = row0 + kg * 4 + r;
        if (orow >= nrows) continue;
        #pragma unroll
        for (int j = 0; j < 8; ++j)
            outb[(size_t)orow * 128 + j * 16 + c] = (ushort)bfbits(acc[j][r]);
    }
}

// -------------------------- JK gemm + pool + (chained next conv0) fused
// A = xsb [nrows x 256] bf16; h = relu(A@Wjk + b) kept in swizzled LDS;
// pool h into z (run-compressed atomics); optionally h @ Wnext -> xwb.
template<bool CHAIN>
__global__ __launch_bounds__(256) void jk_fused_kernel(
    const ushort* __restrict__ xsb, const ushort* __restrict__ wbj,
    const float* __restrict__ jkb,
    const int* __restrict__ batch, float* __restrict__ z, int zoff,
    const ushort* __restrict__ wnext, ushort* __restrict__ xwb_out, int nrows)
{
    __shared__ __align__(16) ushort hl[64 * 128];
    __shared__ int sb[64];
    const int tid  = threadIdx.x;
    const int wid  = tid >> 6;
    const int lane = tid & 63;
    const int rowb = blockIdx.x * 64;
    const int row0 = rowb + wid * 16;
    const int c    = lane & 15;
    const int kg   = lane >> 4;

    if (tid < 64) {
        int rr = rowb + tid;
        sb[tid] = (rr < nrows) ? batch[rr] : -1;
    }
    int arow = row0 + c;
    if (arow >= nrows) arow = nrows - 1;
    const ushort* Aptr = xsb + (size_t)arow * 256 + kg * 8;

    f32x4 acc[8];
    #pragma unroll
    for (int j = 0; j < 8; ++j) acc[j] = (f32x4)0.f;
    for (int t = 0; t < 8; ++t) {                  // nt = 256/32
        short8 a = *(const short8*)(Aptr + t * 32);
        const ushort* Wp = wbj + ((size_t)t * 64 + lane) * 8;
        #pragma unroll
        for (int j = 0; j < 8; ++j) {
            short8 b = *(const short8*)(Wp + (size_t)j * 8 * 512);
            acc[j] = __builtin_amdgcn_mfma_f32_16x16x32_bf16(a, b, acc[j], 0, 0, 0);
        }
    }
    // bias + relu -> swizzled LDS (byte ^= (row&7)<<4)
    #pragma unroll
    for (int r = 0; r < 4; ++r) {
        int rl = wid * 16 + kg * 4 + r;
        #pragma unroll
        for (int j = 0; j < 8; ++j) {
            float v = fmaxf(acc[j][r] + jkb[j * 16 + c], 0.f);
            uint byte = ((uint)(rl * 256 + (j * 16 + c) * 2)) ^ ((uint)(rl & 7) << 4);
            *(ushort*)((char*)hl + byte) = (ushort)bfbits(v);
        }
    }
    __syncthreads();

    if (CHAIN) {                                   // h[64x128] @ Wnext (K=128)
        f32x4 ac2[8];
        #pragma unroll
        for (int j = 0; j < 8; ++j) ac2[j] = (f32x4)0.f;
        int rl2 = wid * 16 + c;
        uint rx = (uint)(rl2 & 7) << 4;
        #pragma unroll
        for (int t = 0; t < 4; ++t) {
            uint byte = ((uint)(rl2 * 256 + (kg * 8 + t * 32) * 2)) ^ rx;
            short8 a = *(const short8*)((char*)hl + byte);
            const ushort* Wp = wnext + ((size_t)t * 64 + lane) * 8;
            #pragma unroll
            for (int j = 0; j < 8; ++j) {
                short8 b = *(const short8*)(Wp + (size_t)j * 4 * 512);
                ac2[j] = __builtin_amdgcn_mfma_f32_16x16x32_bf16(a, b, ac2[j], 0, 0, 0);
            }
        }
        #pragma unroll
        for (int r = 0; r < 4; ++r) {
            int orow = row0 + kg * 4 + r;
            if (orow >= nrows) continue;
            #pragma unroll
            for (int j = 0; j < 8; ++j)
                xwb_out[(size_t)orow * 128 + j * 16 + c] = (ushort)bfbits(ac2[j][r]);
        }
    }

    // pool: threads 0..127, one col each; run-compress over 64 rows
    if (tid < 128) {
        int f = tid;
        int nend = nrows - rowb; if (nend > 64) nend = 64;
        int cur = sb[0];
        float acc2 = 0.f;
        for (int rl = 0; rl < nend; ++rl) {
            int bb = sb[rl];
            if (bb != cur) {
                atomicAdd(&z[(size_t)cur * 384 + zoff + f], acc2);
                acc2 = 0.f; cur = bb;
            }
            uint byte = ((uint)(rl * 256 + f * 2)) ^ ((uint)(rl & 7) << 4);
            acc2 += bf2f(*(const ushort*)((const char*)hl + byte));
        }
        atomicAdd(&z[(size_t)cur * 384 + zoff + f], acc2);
    }
}

// ------------------------------------------------------- sparse aggregation
// one wave per node; lane holds 2 feats. 16-deep gather unroll (MLP).
__global__ __launch_bounds__(256) void agg_kernel(
    const uint* __restrict__ xwb, const int* __restrict__ rowptr,
    const uint* __restrict__ ecv,
    const float* __restrict__ dinv, const float* __restrict__ bias,
    uint* __restrict__ outu, int coff, int n)
{
    int node = (int)((blockIdx.x * (size_t)blockDim.x + threadIdx.x) >> 6);
    int lane = threadIdx.x & 63;
    if (node >= n) return;
    float d = dinv[node];
    uint  g = xwb[(size_t)node * 64 + lane];
    float bx = 0.f, by = 0.f;
    int e0 = rowptr[node], e1 = rowptr[node + 1];
    int e = e0;
    for (; e + 16 <= e1; e += 16) {
        uint rec[16];
        #pragma unroll
        for (int q = 0; q < 16; ++q) rec[q] = ecv[e + q];
        uint gq[16];
        #pragma unroll
        for (int q = 0; q < 16; ++q)
            gq[q] = xwb[(size_t)(rec[q] & 0xffffu) * 64 + lane];
        #pragma unroll
        for (int q = 0; q < 16; ++q) {
            float v = __half2float(__ushort_as_half((ushort)(rec[q] >> 16)));
            bx = fmaf(v, bflo(gq[q]), bx);
            by = fmaf(v, bfhi(gq[q]), by);
        }
    }
    for (; e + 4 <= e1; e += 4) {
        uint rec[4];
        #pragma unroll
        for (int q = 0; q < 4; ++q) rec[q] = ecv[e + q];
        uint gq[4];
        #pragma unroll
        for (int q = 0; q < 4; ++q)
            gq[q] = xwb[(size_t)(rec[q] & 0xffffu) * 64 + lane];
        #pragma unroll
        for (int q = 0; q < 4; ++q) {
            float v = __half2float(__ushort_as_half((ushort)(rec[q] >> 16)));
            bx = fmaf(v, bflo(gq[q]), bx);
            by = fmaf(v, bfhi(gq[q]), by);
        }
    }
    for (; e < e1; ++e) {
        uint rec = ecv[e];
        uint gg = xwb[(size_t)(rec & 0xffffu) * 64 + lane];
        float v = __half2float(__ushort_as_half((ushort)(rec >> 16)));
        bx = fmaf(v, bflo(gg), bx);
        by = fmaf(v, bfhi(gg), by);
    }
    float sw = d * d;
    float ax = fmaf(d, bx, bflo(g) * sw);
    float ay = fmaf(d, by, bfhi(g) * sw);
    float2 b = *(const float2*)&bias[lane * 2];
    ax = fmaxf(ax + b.x, 0.f);
    ay = fmaxf(ay + b.y, 0.f);
    outu[(size_t)node * 128 + coff + lane] = bfbits(ax) | (bfbits(ay) << 16);
}

// ---------------------------------------------------------------- head
__global__ __launch_bounds__(128) void head_kernel(
    const float* __restrict__ z,
    const float* __restrict__ g,  const float* __restrict__ be,
    const float* __restrict__ mu, const float* __restrict__ var,
    const float* __restrict__ w1, const float* __restrict__ b1,
    const float* __restrict__ w2, const float* __restrict__ b2,
    float* __restrict__ out)
{
    int gi = blockIdx.x;
    int t  = threadIdx.x;
    __shared__ float zs[384];
    __shared__ float h1[128];
    __shared__ float lg[10];
    for (int i = t; i < 384; i += 128) {
        float v = z[(size_t)gi * 384 + i];
        v = (v - mu[i]) * rsqrtf(var[i] + 1e-5f) * g[i] + be[i];
        zs[i] = v;
    }
    __syncthreads();
    float acc = b1[t];
    for (int k = 0; k < 384; ++k) acc = fmaf(zs[k], w1[(size_t)k * 128 + t], acc);
    h1[t] = fmaxf(acc, 0.f);
    __syncthreads();
    if (t < 10) {
        float a2 = b2[t];
        for (int k = 0; k < 128; ++k) a2 = fmaf(h1[k], w2[(size_t)k * 10 + t], a2);
        lg[t] = a2;
    }
    __syncthreads();
    if (t == 0) {
        float m = lg[0];
        for (int i = 1; i < 10; ++i) m = fmaxf(m, lg[i]);
        float e[10], s = 0.f;
        for (int i = 0; i < 10; ++i) { e[i] = expf(lg[i] - m); s += e[i]; }
        float inv = 1.f / s;
        for (int i = 0; i < 10; ++i) out[(size_t)gi * 10 + i] = e[i] * inv;
    }
}

// ---------------------------------------------------------------- launch
extern "C" void kernel_launch(void* const* d_in, const int* in_sizes, int n_in,
                              void* d_out, int out_size, void* d_ws, size_t ws_size,
                              hipStream_t stream)
{
    const float* x      = (const float*)d_in[0];
    const float* ea     = (const float*)d_in[1];
    const float* conv_w = (const float*)d_in[2];
    const float* conv_b = (const float*)d_in[3];
    const float* jk_w   = (const float*)d_in[4];
    const float* jk_b   = (const float*)d_in[5];
    const float* bn_g   = (const float*)d_in[6];
    const float* bn_b   = (const float*)d_in[7];
    const float* bn_m   = (const float*)d_in[8];
    const float* bn_v   = (const float*)d_in[9];
    const float* w1     = (const float*)d_in[10];
    const float* b1     = (const float*)d_in[11];
    const float* w2     = (const float*)d_in[12];
    const float* b2     = (const float*)d_in[13];
    const int*   eidx   = (const int*)d_in[14];
    const int*   batch  = (const int*)d_in[15];
    const int* srcv = eidx;
    const int* dstv = eidx + NE;
    float* out = (float*)d_out;

    char* ws = (char*)d_ws;
    size_t off = 0;
    auto alloc = [&](size_t b) { size_t o = off; off += (b + 511) & ~(size_t)511; return o; };
    u64*   pk     = (u64*)  (ws + alloc((size_t)NN * 8));
    float* z      = (float*)(ws + alloc((size_t)NG * 384 * 4));
    uint*  ctr    = (uint*) (ws + alloc(512));
    size_t zero_bytes = off;
    float* dinv   = (float*)(ws + alloc((size_t)NN * 4));
    int*   rowptr = (int*)  (ws + alloc((size_t)(NN + 1) * 4));
    ushort* rankb = (ushort*)(ws + alloc((size_t)NE * 2));
    uint*  ecv    = (uint*) (ws + alloc((size_t)NE * 4));
    ushort* wbc   = (ushort*)(ws + alloc((size_t)6 * 128 * 128 * 2));
    ushort* wbj   = (ushort*)(ws + alloc((size_t)3 * 256 * 128 * 2));
    uint*  xwb    = (uint*) (ws + alloc((size_t)NN * 64 * 4));
    uint*  xsb    = (uint*) (ws + alloc((size_t)NN * 128 * 4));   // [NN][256] bf16
    int*   bsum   = (int*)  (ws + alloc((size_t)256 * 4));
    int*   boff   = (int*)  (ws + alloc((size_t)257 * 4));
    (void)ws_size; (void)in_sizes; (void)n_in; (void)out_size;

    hipMemsetAsync(d_ws, 0, zero_bytes, stream);

    const int NB = (NN + 255) / 256;
    prep_kernel<<<EB + WBC + WBJ, 256, 0, stream>>>(dstv, ea, pk, rankb,
                                                    conv_w, wbc, jk_w, wbj);
    scan_ab_kernel<<<NB, 256, 0, stream>>>(pk, bsum, dinv, boff, ctr, NN, NB);
    scan_final_kernel<<<NB, 256, 0, stream>>>(pk, boff, rowptr, NN, NB);
    fill_kernel<<<EB, 256, 0, stream>>>(srcv, dstv, ea, dinv, rowptr, rankb,
                                        ecv, NE);

    const int GB = (NN + 63) / 64;
    const int AB = (NN * 64 + 255) / 256;

    // layer 0 conv0 from fp32 x
    conv_gemm_kernel<true><<<GB, 256, 0, stream>>>(x, 128, 128, wbc,
                                                   (ushort*)xwb, NN);
    for (int l = 0; l < 3; ++l) {
        agg_kernel<<<AB, 256, 0, stream>>>(
            xwb, rowptr, ecv, dinv, conv_b + (size_t)(l * 2 + 0) * 128,
            xsb, 0, NN);
        conv_gemm_kernel<false><<<GB, 256, 0, stream>>>(
            (const ushort*)xsb, 128, 256, wbc + (size_t)(l * 2 + 1) * 128 * 128,
            (ushort*)xwb, NN);
        agg_kernel<<<AB, 256, 0, stream>>>(
            xwb, rowptr, ecv, dinv, conv_b + (size_t)(l * 2 + 1) * 128,
            xsb, 64, NN);
        if (l < 2) {
            jk_fused_kernel<true><<<GB, 256, 0, stream>>>(
                (const ushort*)xsb, wbj + (size_t)l * 256 * 128,
                jk_b + (size_t)l * 128, batch, z, l * 128,
                wbc + (size_t)(l + 1) * 2 * 128 * 128, (ushort*)xwb, NN);
        } else {
            jk_fused_kernel<false><<<GB, 256, 0, stream>>>(
                (const ushort*)xsb, wbj + (size_t)l * 256 * 128,
                jk_b + (size_t)l * 128, batch, z, l * 128,
                nullptr, nullptr, NN);
        }
    }
    head_kernel<<<NG, 128, 0, stream>>>(z, bn_g, bn_b, bn_m, bn_v,
                                        w1, b1, w2, b2, out);
}